// Round 10
// baseline (1237.417 us; speedup 1.0000x reference)
//
#include <hip/hip_runtime.h>
#include <math.h>

#define N_V    100000
#define N_E    200000
#define NNZ_C  1600000
#define NFEAT  128
#define NHID   64
#define NCLASS 40
#define NLAYER 8
#define ALPHA  0.1f

typedef _Float16 f16;
typedef _Float16 f16x8 __attribute__((ext_vector_type(8)));   // 16 B per lane

// ---------------------------------------------------------------------------
// histogram incidences per edge AND per vertex (streaming reads -> nt loads)
__global__ __launch_bounds__(256) void k_count2(const int* __restrict__ vertex,
                                                const int* __restrict__ edges,
                                                int* __restrict__ cntE,
                                                int* __restrict__ cntV) {
    int z = blockIdx.x * blockDim.x + threadIdx.x;
    if (z < NNZ_C) {
        int e = __builtin_nontemporal_load(&edges[z]);
        int v = __builtin_nontemporal_load(&vertex[z]);
        atomicAdd(&cntE[e], 1);
        atomicAdd(&cntV[v], 1);
    }
}

// exclusive scan over n ints, 1024 elements per block (256 thr x 4 elems)
__global__ __launch_bounds__(256) void k_scan_partial(const int* __restrict__ in,
                                                      int* __restrict__ out,
                                                      int* __restrict__ blockSums,
                                                      int n) {
    __shared__ int sd[256];
    const int t = threadIdx.x;
    const int base = blockIdx.x * 1024 + t * 4;
    int v0 = (base + 0 < n) ? in[base + 0] : 0;
    int v1 = (base + 1 < n) ? in[base + 1] : 0;
    int v2 = (base + 2 < n) ? in[base + 2] : 0;
    int v3 = (base + 3 < n) ? in[base + 3] : 0;
    int s = v0 + v1 + v2 + v3;
    sd[t] = s;
    __syncthreads();
    #pragma unroll
    for (int off = 1; off < 256; off <<= 1) {
        int x = (t >= off) ? sd[t - off] : 0;
        __syncthreads();
        sd[t] += x;
        __syncthreads();
    }
    if (blockSums && t == 255) blockSums[blockIdx.x] = sd[255];
    int run = sd[t] - s;                 // exclusive prefix of this thread
    if (base + 0 < n) out[base + 0] = run; run += v0;
    if (base + 1 < n) out[base + 1] = run; run += v1;
    if (base + 2 < n) out[base + 2] = run; run += v2;
    if (base + 3 < n) out[base + 3] = run;
}

__global__ __launch_bounds__(256) void k_scan_add(int* __restrict__ data,
                                                  const int* __restrict__ bsOff,
                                                  int n) {
    const int base = blockIdx.x * 1024 + threadIdx.x * 4;
    const int add = bsOff[blockIdx.x];
    #pragma unroll
    for (int j = 0; j < 4; ++j)
        if (base + j < n) data[base + j] += add;
}

// factorE = degE / count; finalize CSR sentinels; zero both fill cursors
// (replaces two hipMemsetAsync launches)
__global__ __launch_bounds__(256) void k_factor(const int* __restrict__ counts,
                                                const float* __restrict__ degE,
                                                float* __restrict__ factorE,
                                                int* __restrict__ offE,
                                                int* __restrict__ offV,
                                                int* __restrict__ curE,
                                                int* __restrict__ curV) {
    int e = blockIdx.x * blockDim.x + threadIdx.x;
    if (e == 0) { offE[N_E] = NNZ_C; offV[N_V] = NNZ_C; }
    if (e < N_E) {
        int c = counts[e];
        factorE[e] = (c > 0) ? degE[e] / (float)c : 0.0f;
        curE[e] = 0;
    }
    if (e < N_V) curV[e] = 0;
}

// fill both adjacency lists. Random 4 B stores: NONTEMPORAL so they bypass
// L2 allocation and merge byte-enabled in the memory-side LLC (kills the
// 64 B/store partial-line writeback amplification: 205 MB -> ~13 MB).
__global__ __launch_bounds__(256) void k_fill(const int* __restrict__ vertex,
                                              const int* __restrict__ edges,
                                              const int* __restrict__ offE,
                                              const int* __restrict__ offV,
                                              int* __restrict__ curE,
                                              int* __restrict__ curV,
                                              int* __restrict__ adjV,
                                              int* __restrict__ adjE) {
    int z = blockIdx.x * blockDim.x + threadIdx.x;
    if (z < NNZ_C) {
        int v = __builtin_nontemporal_load(&vertex[z]);
        int e = __builtin_nontemporal_load(&edges[z]);
        int pe = atomicAdd(&curE[e], 1);
        __builtin_nontemporal_store(v, &adjV[offE[e] + pe]);
        int pv = atomicAdd(&curV[v], 1);
        __builtin_nontemporal_store(e, &adjE[offV[v] + pv]);
    }
}

// h = relu(x @ W0 + b0) -> fp16; also copy to h0. One wave per row, lane = feature.
__global__ __launch_bounds__(256) void k_lin(const float* __restrict__ x,
                                             const float* __restrict__ W0,
                                             const float* __restrict__ b0,
                                             f16* __restrict__ h,
                                             f16* __restrict__ h0) {
    __shared__ float sW[NFEAT * NHID];   // 32 KB
    __shared__ float sb[NHID];
    for (int i = threadIdx.x; i < NFEAT * NHID; i += blockDim.x) sW[i] = W0[i];
    if (threadIdx.x < NHID) sb[threadIdx.x] = b0[threadIdx.x];
    __syncthreads();
    const int wid = threadIdx.x >> 6;
    const int f   = threadIdx.x & 63;
    const int wpb = blockDim.x >> 6;
    for (int n = blockIdx.x * wpb + wid; n < N_V; n += gridDim.x * wpb) {
        const float* xr = x + (size_t)n * NFEAT;
        float acc = sb[f];
        #pragma unroll 8
        for (int k = 0; k < NFEAT; ++k) acc = fmaf(xr[k], sW[k * NHID + f], acc);
        f16 r = (f16)fmaxf(acc, 0.0f);
        __builtin_nontemporal_store(r, &h [(size_t)n * NHID + f]);
        __builtin_nontemporal_store(r, &h0[(size_t)n * NHID + f]);
    }
}

// Xe[e] = (sum over incident vertices of h[v]) * factorE[e]
// 8-lane-subgroup-per-edge, 8-deep masked batch -> 64 rows in flight/wave.
// adjV is streaming (nt load); h gathers stay cached (want L2 hits).
__global__ __launch_bounds__(256) void k_edge_gather(const int* __restrict__ offE,
                                                     const int* __restrict__ adjV,
                                                     const float* __restrict__ factorE,
                                                     const f16* __restrict__ h,
                                                     f16* __restrict__ Xe) {
    const int lane = threadIdx.x & 63;
    const int sg = lane >> 3, t = lane & 7;
    const int e = (blockIdx.x * 4 + (threadIdx.x >> 6)) * 8 + sg;  // 32 edges/block
    if (e >= N_E) return;
    const f16x8* __restrict__ hv = (const f16x8*)h;
    const int s   = offE[e];
    const int cnt = offE[e + 1] - s;
    const float fac = factorE[e];
    float acc[8] = {0.f, 0.f, 0.f, 0.f, 0.f, 0.f, 0.f, 0.f};
    for (int w = 0; w < cnt; w += 8) {          // w<cnt guards cnt==0
        int   idx[8];
        float msk[8];
        f16x8 v[8];
        #pragma unroll
        for (int r = 0; r < 8; ++r) {
            int cr = min(w + r, cnt - 1);
            idx[r] = __builtin_nontemporal_load(&adjV[s + cr]);
            msk[r] = (r == 0 || w + r < cnt) ? 1.f : 0.f;
        }
        #pragma unroll
        for (int r = 0; r < 8; ++r) v[r] = hv[(size_t)idx[r] * 8 + t];
        #pragma unroll
        for (int j = 0; j < 8; ++j) {
            #pragma unroll
            for (int r = 0; r < 8; ++r)
                acc[j] = fmaf(msk[r], (float)v[r][j], acc[j]);
        }
    }
    f16x8 o;
    #pragma unroll
    for (int j = 0; j < 8; ++j) o[j] = (f16)(acc[j] * fac);
    __builtin_nontemporal_store(o, &((f16x8*)Xe)[(size_t)e * 8 + t]);
}

// Fused: Xv = (sum over incident edges of Xe[e]) * degV  ->  L2 rownorm ->
// GCNII mix -> 64x64 GEMM -> relu -> fp16. 8-lane-subgroup-per-vertex,
// 8-deep masked batch. adjE/h0 streaming (nt); Xe gathers cached.
__global__ __launch_bounds__(256) void k_vertex_update(const int* __restrict__ offV,
                                                       const int* __restrict__ adjE,
                                                       const f16* __restrict__ Xe,
                                                       const float* __restrict__ degV,
                                                       const f16* __restrict__ h0,
                                                       const float* __restrict__ Wi,
                                                       float beta,
                                                       f16* __restrict__ h) {
    __shared__ float sW[NHID * NHID];    // 16 KB, row-major [k][f]
    for (int i = threadIdx.x; i < NHID * NHID; i += blockDim.x) sW[i] = Wi[i];
    __syncthreads();
    const int lane = threadIdx.x & 63;
    const int sg = lane >> 3, t = lane & 7;
    const int n = (blockIdx.x * 4 + (threadIdx.x >> 6)) * 8 + sg; // 32 verts/block
    if (n >= N_V) return;
    const f16x8* __restrict__ xe = (const f16x8*)Xe;
    const int s   = offV[n];
    const int cnt = offV[n + 1] - s;
    const float dv = degV[n];
    const f16x8 h0v = __builtin_nontemporal_load(&((const f16x8*)h0)[(size_t)n * 8 + t]);
    float acc[8] = {0.f, 0.f, 0.f, 0.f, 0.f, 0.f, 0.f, 0.f};
    for (int w = 0; w < cnt; w += 8) {
        int   idx[8];
        float msk[8];
        f16x8 v[8];
        #pragma unroll
        for (int r = 0; r < 8; ++r) {
            int cr = min(w + r, cnt - 1);
            idx[r] = __builtin_nontemporal_load(&adjE[s + cr]);
            msk[r] = (r == 0 || w + r < cnt) ? 1.f : 0.f;
        }
        #pragma unroll
        for (int r = 0; r < 8; ++r) v[r] = xe[(size_t)idx[r] * 8 + t];
        #pragma unroll
        for (int j = 0; j < 8; ++j) {
            #pragma unroll
            for (int r = 0; r < 8; ++r)
                acc[j] = fmaf(msk[r], (float)v[r][j], acc[j]);
        }
    }
    // scale by degV FIRST, then norm of the scaled row (matches reference)
    float xv[8], ss = 0.f;
    #pragma unroll
    for (int j = 0; j < 8; ++j) { xv[j] = acc[j] * dv; ss = fmaf(xv[j], xv[j], ss); }
    #pragma unroll
    for (int off = 1; off <= 4; off <<= 1)   // reduce within the 8-lane subgroup
        ss += __shfl_xor(ss, off, 64);
    float rn  = sqrtf(ss);
    float inv = (rn > 0.0f) ? 1.0f / rn : 0.0f;
    float xi[8];
    #pragma unroll
    for (int j = 0; j < 8; ++j)
        xi[j] = (1.0f - ALPHA) * (xv[j] * inv) + ALPHA * (float)h0v[j];
    // y_f = sum_k xi_k * W[k][f], f = 8t+j; xi_k owned by lane 8*sg+(k>>3),
    // component k&7. Uniform k-loop; LDS float4 reads are 2-way alias (free).
    float y[8] = {0.f, 0.f, 0.f, 0.f, 0.f, 0.f, 0.f, 0.f};
    #pragma unroll
    for (int k = 0; k < NHID; ++k) {
        float xk = __shfl(xi[k & 7], 8 * sg + (k >> 3), 64);
        const float4 wa = *(const float4*)&sW[k * NHID + 8 * t];
        const float4 wb = *(const float4*)&sW[k * NHID + 8 * t + 4];
        y[0] = fmaf(xk, wa.x, y[0]);
        y[1] = fmaf(xk, wa.y, y[1]);
        y[2] = fmaf(xk, wa.z, y[2]);
        y[3] = fmaf(xk, wa.w, y[3]);
        y[4] = fmaf(xk, wb.x, y[4]);
        y[5] = fmaf(xk, wb.y, y[5]);
        y[6] = fmaf(xk, wb.z, y[6]);
        y[7] = fmaf(xk, wb.w, y[7]);
    }
    f16x8 o;
    #pragma unroll
    for (int j = 0; j < 8; ++j) {
        float v = fmaf(beta, y[j] - xi[j], xi[j]);   // (1-b)*xi + b*y
        o[j] = (f16)fmaxf(v, 0.0f);
    }
    __builtin_nontemporal_store(o, &((f16x8*)h)[(size_t)n * 8 + t]);
}

// out = h @ Wout + bout. One wave per row; lanes 0..39 hold the classes.
__global__ __launch_bounds__(256) void k_out(const f16* __restrict__ h,
                                             const float* __restrict__ Wout,
                                             const float* __restrict__ bout,
                                             float* __restrict__ out) {
    __shared__ float sW[NHID * NCLASS];  // 10 KB
    __shared__ float sb[NCLASS];
    for (int i = threadIdx.x; i < NHID * NCLASS; i += blockDim.x) sW[i] = Wout[i];
    if (threadIdx.x < NCLASS) sb[threadIdx.x] = bout[threadIdx.x];
    __syncthreads();
    const int wid = threadIdx.x >> 6;
    const int f   = threadIdx.x & 63;
    const int wpb = blockDim.x >> 6;
    const int c   = (f < NCLASS) ? f : 0;
    for (int n = blockIdx.x * wpb + wid; n < N_V; n += gridDim.x * wpb) {
        float hv = (float)h[(size_t)n * NHID + f];
        float y  = sb[c];
        #pragma unroll 8
        for (int k = 0; k < NHID; ++k)
            y = fmaf(__shfl(hv, k, 64), sW[k * NCLASS + c], y);
        if (f < NCLASS) out[(size_t)n * NCLASS + f] = y;
    }
}

// ---------------------------------------------------------------------------
extern "C" void kernel_launch(void* const* d_in, const int* in_sizes, int n_in,
                              void* d_out, int out_size, void* d_ws, size_t ws_size,
                              hipStream_t stream) {
    const float* x      = (const float*)d_in[0];
    const int*   vertex = (const int*)  d_in[1];
    const int*   edges  = (const int*)  d_in[2];
    const float* degE   = (const float*)d_in[3];
    const float* degV   = (const float*)d_in[4];
    const float* W0     = (const float*)d_in[5];
    const float* b0     = (const float*)d_in[6];
    const float* Ws     = (const float*)d_in[7];
    const float* Wout   = (const float*)d_in[8];
    const float* bout   = (const float*)d_in[9];
    float* out = (float*)d_out;

    // workspace carve-up (~66 MB)
    char* p = (char*)d_ws;
    auto carve = [&](size_t bytes) { char* r = p; p += (bytes + 255) & ~(size_t)255; return r; };
    f16*   h0      = (f16*)  carve((size_t)N_V * NHID * sizeof(f16));
    f16*   hA      = (f16*)  carve((size_t)N_V * NHID * sizeof(f16));
    f16*   Xe      = (f16*)  carve((size_t)N_E * NHID * sizeof(f16));
    float* factorE = (float*)carve((size_t)N_E * sizeof(float));
    int*   offE    = (int*)  carve((size_t)(N_E + 1) * sizeof(int));
    int*   offV    = (int*)  carve((size_t)(N_V + 1) * sizeof(int));
    int*   cntE    = (int*)  carve((size_t)N_E * sizeof(int));   // reused as cursor
    int*   cntV    = (int*)  carve((size_t)N_V * sizeof(int));   // contiguous after cntE
    int*   adjV    = (int*)  carve((size_t)NNZ_C * sizeof(int));
    int*   adjE    = (int*)  carve((size_t)NNZ_C * sizeof(int));
    int*   bsE     = (int*)  carve(256 * sizeof(int));
    int*   bsOffE  = (int*)  carve(256 * sizeof(int));
    int*   bsV     = (int*)  carve(256 * sizeof(int));
    int*   bsOffV  = (int*)  carve(256 * sizeof(int));

    const int scanBlocksE = (N_E + 1023) / 1024;   // 196
    const int scanBlocksV = (N_V + 1023) / 1024;   // 98

    // ---- one-time CSR build (per call) ----
    // N_E*4 = 800000 bytes is 256-aligned, so cntV directly follows cntE:
    hipMemsetAsync(cntE, 0, (size_t)(N_E + N_V) * sizeof(int), stream);
    k_count2<<<(NNZ_C + 255) / 256, 256, 0, stream>>>(vertex, edges, cntE, cntV);

    k_scan_partial<<<scanBlocksE, 256, 0, stream>>>(cntE, offE, bsE, N_E);
    k_scan_partial<<<1,           256, 0, stream>>>(bsE, bsOffE, nullptr, scanBlocksE);
    k_scan_add    <<<scanBlocksE, 256, 0, stream>>>(offE, bsOffE, N_E);

    k_scan_partial<<<scanBlocksV, 256, 0, stream>>>(cntV, offV, bsV, N_V);
    k_scan_partial<<<1,           256, 0, stream>>>(bsV, bsOffV, nullptr, scanBlocksV);
    k_scan_add    <<<scanBlocksV, 256, 0, stream>>>(offV, bsOffV, N_V);

    // computes factorE, finalizes sentinels, zeroes both cursors
    k_factor<<<(N_E + 255) / 256, 256, 0, stream>>>(cntE, degE, factorE,
                                                    offE, offV, cntE, cntV);

    k_fill<<<(NNZ_C + 255) / 256, 256, 0, stream>>>(vertex, edges, offE, offV,
                                                    cntE, cntV, adjV, adjE);

    // ---- network ----
    k_lin<<<2048, 256, 0, stream>>>(x, W0, b0, hA, h0);

    for (int i = 0; i < NLAYER; ++i) {
        float beta = (float)log(0.5 / (double)(i + 1) + 1.0);
        k_edge_gather  <<<(N_E + 31) / 32, 256, 0, stream>>>(offE, adjV, factorE, hA, Xe);
        k_vertex_update<<<(N_V + 31) / 32, 256, 0, stream>>>(offV, adjE, Xe, degV, h0,
                                                             Ws + (size_t)i * NHID * NHID,
                                                             beta, hA);
    }
    k_out<<<4096, 256, 0, stream>>>(hA, Wout, bout, out);
}

// Round 11
// 1178.213 us; speedup vs baseline: 1.0502x; 1.0502x over previous
//
#include <hip/hip_runtime.h>
#include <math.h>

#define N_V    100000
#define N_E    200000
#define NNZ_C  1600000
#define NFEAT  128
#define NHID   64
#define NCLASS 40
#define NLAYER 8
#define ALPHA  0.1f

#define NWIN   8                 // one adjacency window per XCD
#define WE     (N_E / NWIN)      // 25000 edges per window
#define WV     (N_V / NWIN)      // 12500 vertices per window

typedef _Float16 f16;
typedef _Float16 f16x8 __attribute__((ext_vector_type(8)));   // 16 B per lane

// ---------------------------------------------------------------------------
// histogram incidences per edge AND per vertex (streaming reads -> nt loads)
__global__ __launch_bounds__(256) void k_count2(const int* __restrict__ vertex,
                                                const int* __restrict__ edges,
                                                int* __restrict__ cntE,
                                                int* __restrict__ cntV) {
    int z = blockIdx.x * blockDim.x + threadIdx.x;
    if (z < NNZ_C) {
        int e = __builtin_nontemporal_load(&edges[z]);
        int v = __builtin_nontemporal_load(&vertex[z]);
        atomicAdd(&cntE[e], 1);
        atomicAdd(&cntV[v], 1);
    }
}

// exclusive scan over n ints, 1024 elements per block (256 thr x 4 elems)
__global__ __launch_bounds__(256) void k_scan_partial(const int* __restrict__ in,
                                                      int* __restrict__ out,
                                                      int* __restrict__ blockSums,
                                                      int n) {
    __shared__ int sd[256];
    const int t = threadIdx.x;
    const int base = blockIdx.x * 1024 + t * 4;
    int v0 = (base + 0 < n) ? in[base + 0] : 0;
    int v1 = (base + 1 < n) ? in[base + 1] : 0;
    int v2 = (base + 2 < n) ? in[base + 2] : 0;
    int v3 = (base + 3 < n) ? in[base + 3] : 0;
    int s = v0 + v1 + v2 + v3;
    sd[t] = s;
    __syncthreads();
    #pragma unroll
    for (int off = 1; off < 256; off <<= 1) {
        int x = (t >= off) ? sd[t - off] : 0;
        __syncthreads();
        sd[t] += x;
        __syncthreads();
    }
    if (blockSums && t == 255) blockSums[blockIdx.x] = sd[255];
    int run = sd[t] - s;                 // exclusive prefix of this thread
    if (base + 0 < n) out[base + 0] = run; run += v0;
    if (base + 1 < n) out[base + 1] = run; run += v1;
    if (base + 2 < n) out[base + 2] = run; run += v2;
    if (base + 3 < n) out[base + 3] = run;
}

__global__ __launch_bounds__(256) void k_scan_add(int* __restrict__ data,
                                                  const int* __restrict__ bsOff,
                                                  int n) {
    const int base = blockIdx.x * 1024 + threadIdx.x * 4;
    const int add = bsOff[blockIdx.x];
    #pragma unroll
    for (int j = 0; j < 4; ++j)
        if (base + j < n) data[base + j] += add;
}

// factorE = degE / count; finalize CSR sentinels; zero both fill cursors
__global__ __launch_bounds__(256) void k_factor(const int* __restrict__ counts,
                                                const float* __restrict__ degE,
                                                float* __restrict__ factorE,
                                                int* __restrict__ offE,
                                                int* __restrict__ offV,
                                                int* __restrict__ curE,
                                                int* __restrict__ curV) {
    int e = blockIdx.x * blockDim.x + threadIdx.x;
    if (e == 0) { offE[N_E] = NNZ_C; offV[N_V] = NNZ_C; }
    if (e < N_E) {
        int c = counts[e];
        factorE[e] = (c > 0) ? degE[e] / (float)c : 0.0f;
        curE[e] = 0;
    }
    if (e < N_V) curV[e] = 0;
}

// XCD-affine WINDOWED fill. Window w is processed only by blocks with
// blockIdx.x&7==w (round-robin XCD dispatch => same XCD). Each window's
// adjacency slice (~1.6 MB) stays resident in that XCD's 4 MiB L2, so
// 64 B lines accumulate ~16 stores before ONE writeback — kills the
// one-writeback-per-4B-store amplification (208 MB -> ~15 MB).
// Cost: each window group streams the full incidence arrays (8x12.8 MB,
// nt loads). Cursor order is arbitrary -> fp-sum rounding only.
__global__ __launch_bounds__(256) void k_fill_win(const int* __restrict__ vertex,
                                                  const int* __restrict__ edges,
                                                  const int* __restrict__ offE,
                                                  const int* __restrict__ offV,
                                                  int* __restrict__ curE,
                                                  int* __restrict__ curV,
                                                  int* __restrict__ adjV,
                                                  int* __restrict__ adjE) {
    const int win  = blockIdx.x & (NWIN - 1);
    const int blk  = blockIdx.x >> 3;
    const int nblk = gridDim.x >> 3;
    const int eLo = win * WE, eHi = eLo + WE;
    const int vLo = win * WV, vHi = vLo + WV;
    for (int z = blk * blockDim.x + threadIdx.x; z < NNZ_C; z += nblk * blockDim.x) {
        int v = __builtin_nontemporal_load(&vertex[z]);
        int e = __builtin_nontemporal_load(&edges[z]);
        if (e >= eLo && e < eHi) {
            int pe = atomicAdd(&curE[e], 1);
            adjV[offE[e] + pe] = v;          // NORMAL store: want L2 merging
        }
        if (v >= vLo && v < vHi) {
            int pv = atomicAdd(&curV[v], 1);
            adjE[offV[v] + pv] = e;
        }
    }
}

// h = relu(x @ W0 + b0) -> fp16; also copy to h0. One wave per row, lane = feature.
__global__ __launch_bounds__(256) void k_lin(const float* __restrict__ x,
                                             const float* __restrict__ W0,
                                             const float* __restrict__ b0,
                                             f16* __restrict__ h,
                                             f16* __restrict__ h0) {
    __shared__ float sW[NFEAT * NHID];   // 32 KB
    __shared__ float sb[NHID];
    for (int i = threadIdx.x; i < NFEAT * NHID; i += blockDim.x) sW[i] = W0[i];
    if (threadIdx.x < NHID) sb[threadIdx.x] = b0[threadIdx.x];
    __syncthreads();
    const int wid = threadIdx.x >> 6;
    const int f   = threadIdx.x & 63;
    const int wpb = blockDim.x >> 6;
    for (int n = blockIdx.x * wpb + wid; n < N_V; n += gridDim.x * wpb) {
        const float* xr = x + (size_t)n * NFEAT;
        float acc = sb[f];
        #pragma unroll 8
        for (int k = 0; k < NFEAT; ++k) acc = fmaf(xr[k], sW[k * NHID + f], acc);
        f16 r = (f16)fmaxf(acc, 0.0f);
        h [(size_t)n * NHID + f] = r;
        h0[(size_t)n * NHID + f] = r;
    }
}

// Xe[e] = (sum over incident vertices of h[v]) * factorE[e]
// 8-lane-subgroup-per-edge, 4-deep masked batch (avg edge degree = 8;
// 8-deep regressed in round 10 — half the batch was masked duplicates).
__global__ __launch_bounds__(256) void k_edge_gather(const int* __restrict__ offE,
                                                     const int* __restrict__ adjV,
                                                     const float* __restrict__ factorE,
                                                     const f16* __restrict__ h,
                                                     f16* __restrict__ Xe) {
    const int lane = threadIdx.x & 63;
    const int sg = lane >> 3, t = lane & 7;
    const int e = (blockIdx.x * 4 + (threadIdx.x >> 6)) * 8 + sg;  // 32 edges/block
    if (e >= N_E) return;
    const f16x8* __restrict__ hv = (const f16x8*)h;
    const int s   = offE[e];
    const int cnt = offE[e + 1] - s;
    const float fac = factorE[e];
    float acc[8] = {0.f, 0.f, 0.f, 0.f, 0.f, 0.f, 0.f, 0.f};
    for (int w = 0; w < cnt; w += 4) {
        int c1 = min(w + 1, cnt - 1);
        int c2 = min(w + 2, cnt - 1);
        int c3 = min(w + 3, cnt - 1);
        int i0 = adjV[s + w];
        int i1 = adjV[s + c1];
        int i2 = adjV[s + c2];
        int i3 = adjV[s + c3];
        float m1 = (w + 1 < cnt) ? 1.f : 0.f;
        float m2 = (w + 2 < cnt) ? 1.f : 0.f;
        float m3 = (w + 3 < cnt) ? 1.f : 0.f;
        f16x8 v0 = hv[(size_t)i0 * 8 + t];
        f16x8 v1 = hv[(size_t)i1 * 8 + t];
        f16x8 v2 = hv[(size_t)i2 * 8 + t];
        f16x8 v3 = hv[(size_t)i3 * 8 + t];
        #pragma unroll
        for (int j = 0; j < 8; ++j) {
            acc[j] += (float)v0[j];
            acc[j] = fmaf(m1, (float)v1[j], acc[j]);
            acc[j] = fmaf(m2, (float)v2[j], acc[j]);
            acc[j] = fmaf(m3, (float)v3[j], acc[j]);
        }
    }
    f16x8 o;
    #pragma unroll
    for (int j = 0; j < 8; ++j) o[j] = (f16)(acc[j] * fac);
    ((f16x8*)Xe)[(size_t)e * 8 + t] = o;
}

// Fused: Xv = (sum over incident edges of Xe[e]) * degV  ->  L2 rownorm ->
// GCNII mix -> 64x64 GEMM -> relu -> fp16. 8-lane-subgroup-per-vertex,
// 8-deep masked batch (avg vertex degree = 16).
__global__ __launch_bounds__(256) void k_vertex_update(const int* __restrict__ offV,
                                                       const int* __restrict__ adjE,
                                                       const f16* __restrict__ Xe,
                                                       const float* __restrict__ degV,
                                                       const f16* __restrict__ h0,
                                                       const float* __restrict__ Wi,
                                                       float beta,
                                                       f16* __restrict__ h) {
    __shared__ float sW[NHID * NHID];    // 16 KB, row-major [k][f]
    for (int i = threadIdx.x; i < NHID * NHID; i += blockDim.x) sW[i] = Wi[i];
    __syncthreads();
    const int lane = threadIdx.x & 63;
    const int sg = lane >> 3, t = lane & 7;
    const int n = (blockIdx.x * 4 + (threadIdx.x >> 6)) * 8 + sg; // 32 verts/block
    if (n >= N_V) return;
    const f16x8* __restrict__ xe = (const f16x8*)Xe;
    const int s   = offV[n];
    const int cnt = offV[n + 1] - s;
    const float dv = degV[n];
    const f16x8 h0v = ((const f16x8*)h0)[(size_t)n * 8 + t];
    float acc[8] = {0.f, 0.f, 0.f, 0.f, 0.f, 0.f, 0.f, 0.f};
    for (int w = 0; w < cnt; w += 8) {
        int   idx[8];
        float msk[8];
        f16x8 v[8];
        #pragma unroll
        for (int r = 0; r < 8; ++r) {
            int cr = min(w + r, cnt - 1);
            idx[r] = adjE[s + cr];
            msk[r] = (r == 0 || w + r < cnt) ? 1.f : 0.f;
        }
        #pragma unroll
        for (int r = 0; r < 8; ++r) v[r] = xe[(size_t)idx[r] * 8 + t];
        #pragma unroll
        for (int j = 0; j < 8; ++j) {
            #pragma unroll
            for (int r = 0; r < 8; ++r)
                acc[j] = fmaf(msk[r], (float)v[r][j], acc[j]);
        }
    }
    // scale by degV FIRST, then norm of the scaled row (matches reference)
    float xv[8], ss = 0.f;
    #pragma unroll
    for (int j = 0; j < 8; ++j) { xv[j] = acc[j] * dv; ss = fmaf(xv[j], xv[j], ss); }
    #pragma unroll
    for (int off = 1; off <= 4; off <<= 1)   // reduce within the 8-lane subgroup
        ss += __shfl_xor(ss, off, 64);
    float rn  = sqrtf(ss);
    float inv = (rn > 0.0f) ? 1.0f / rn : 0.0f;
    float xi[8];
    #pragma unroll
    for (int j = 0; j < 8; ++j)
        xi[j] = (1.0f - ALPHA) * (xv[j] * inv) + ALPHA * (float)h0v[j];
    // y_f = sum_k xi_k * W[k][f], f = 8t+j; xi_k owned by lane 8*sg+(k>>3),
    // component k&7. Uniform k-loop; LDS float4 reads are 2-way alias (free).
    float y[8] = {0.f, 0.f, 0.f, 0.f, 0.f, 0.f, 0.f, 0.f};
    #pragma unroll
    for (int k = 0; k < NHID; ++k) {
        float xk = __shfl(xi[k & 7], 8 * sg + (k >> 3), 64);
        const float4 wa = *(const float4*)&sW[k * NHID + 8 * t];
        const float4 wb = *(const float4*)&sW[k * NHID + 8 * t + 4];
        y[0] = fmaf(xk, wa.x, y[0]);
        y[1] = fmaf(xk, wa.y, y[1]);
        y[2] = fmaf(xk, wa.z, y[2]);
        y[3] = fmaf(xk, wa.w, y[3]);
        y[4] = fmaf(xk, wb.x, y[4]);
        y[5] = fmaf(xk, wb.y, y[5]);
        y[6] = fmaf(xk, wb.z, y[6]);
        y[7] = fmaf(xk, wb.w, y[7]);
    }
    f16x8 o;
    #pragma unroll
    for (int j = 0; j < 8; ++j) {
        float v = fmaf(beta, y[j] - xi[j], xi[j]);   // (1-b)*xi + b*y
        o[j] = (f16)fmaxf(v, 0.0f);
    }
    ((f16x8*)h)[(size_t)n * 8 + t] = o;
}

// out = h @ Wout + bout. One wave per row; lanes 0..39 hold the classes.
__global__ __launch_bounds__(256) void k_out(const f16* __restrict__ h,
                                             const float* __restrict__ Wout,
                                             const float* __restrict__ bout,
                                             float* __restrict__ out) {
    __shared__ float sW[NHID * NCLASS];  // 10 KB
    __shared__ float sb[NCLASS];
    for (int i = threadIdx.x; i < NHID * NCLASS; i += blockDim.x) sW[i] = Wout[i];
    if (threadIdx.x < NCLASS) sb[threadIdx.x] = bout[threadIdx.x];
    __syncthreads();
    const int wid = threadIdx.x >> 6;
    const int f   = threadIdx.x & 63;
    const int wpb = blockDim.x >> 6;
    const int c   = (f < NCLASS) ? f : 0;
    for (int n = blockIdx.x * wpb + wid; n < N_V; n += gridDim.x * wpb) {
        float hv = (float)h[(size_t)n * NHID + f];
        float y  = sb[c];
        #pragma unroll 8
        for (int k = 0; k < NHID; ++k)
            y = fmaf(__shfl(hv, k, 64), sW[k * NCLASS + c], y);
        if (f < NCLASS) out[(size_t)n * NCLASS + f] = y;
    }
}

// ---------------------------------------------------------------------------
extern "C" void kernel_launch(void* const* d_in, const int* in_sizes, int n_in,
                              void* d_out, int out_size, void* d_ws, size_t ws_size,
                              hipStream_t stream) {
    const float* x      = (const float*)d_in[0];
    const int*   vertex = (const int*)  d_in[1];
    const int*   edges  = (const int*)  d_in[2];
    const float* degE   = (const float*)d_in[3];
    const float* degV   = (const float*)d_in[4];
    const float* W0     = (const float*)d_in[5];
    const float* b0     = (const float*)d_in[6];
    const float* Ws     = (const float*)d_in[7];
    const float* Wout   = (const float*)d_in[8];
    const float* bout   = (const float*)d_in[9];
    float* out = (float*)d_out;

    // workspace carve-up (~66 MB)
    char* p = (char*)d_ws;
    auto carve = [&](size_t bytes) { char* r = p; p += (bytes + 255) & ~(size_t)255; return r; };
    f16*   h0      = (f16*)  carve((size_t)N_V * NHID * sizeof(f16));
    f16*   hA      = (f16*)  carve((size_t)N_V * NHID * sizeof(f16));
    f16*   Xe      = (f16*)  carve((size_t)N_E * NHID * sizeof(f16));
    float* factorE = (float*)carve((size_t)N_E * sizeof(float));
    int*   offE    = (int*)  carve((size_t)(N_E + 1) * sizeof(int));
    int*   offV    = (int*)  carve((size_t)(N_V + 1) * sizeof(int));
    int*   cntE    = (int*)  carve((size_t)N_E * sizeof(int));   // reused as cursor
    int*   cntV    = (int*)  carve((size_t)N_V * sizeof(int));   // contiguous after cntE
    int*   adjV    = (int*)  carve((size_t)NNZ_C * sizeof(int));
    int*   adjE    = (int*)  carve((size_t)NNZ_C * sizeof(int));
    int*   bsE     = (int*)  carve(256 * sizeof(int));
    int*   bsOffE  = (int*)  carve(256 * sizeof(int));
    int*   bsV     = (int*)  carve(256 * sizeof(int));
    int*   bsOffV  = (int*)  carve(256 * sizeof(int));

    const int scanBlocksE = (N_E + 1023) / 1024;   // 196
    const int scanBlocksV = (N_V + 1023) / 1024;   // 98

    // ---- one-time CSR build (per call) ----
    // N_E*4 = 800000 bytes is 256-aligned, so cntV directly follows cntE:
    hipMemsetAsync(cntE, 0, (size_t)(N_E + N_V) * sizeof(int), stream);
    k_count2<<<(NNZ_C + 255) / 256, 256, 0, stream>>>(vertex, edges, cntE, cntV);

    k_scan_partial<<<scanBlocksE, 256, 0, stream>>>(cntE, offE, bsE, N_E);
    k_scan_partial<<<1,           256, 0, stream>>>(bsE, bsOffE, nullptr, scanBlocksE);
    k_scan_add    <<<scanBlocksE, 256, 0, stream>>>(offE, bsOffE, N_E);

    k_scan_partial<<<scanBlocksV, 256, 0, stream>>>(cntV, offV, bsV, N_V);
    k_scan_partial<<<1,           256, 0, stream>>>(bsV, bsOffV, nullptr, scanBlocksV);
    k_scan_add    <<<scanBlocksV, 256, 0, stream>>>(offV, bsOffV, N_V);

    // computes factorE, finalizes sentinels, zeroes both cursors
    k_factor<<<(N_E + 255) / 256, 256, 0, stream>>>(cntE, degE, factorE,
                                                    offE, offV, cntE, cntV);

    // windowed XCD-affine fill: 8 windows x 256 blocks
    k_fill_win<<<NWIN * 256, 256, 0, stream>>>(vertex, edges, offE, offV,
                                               cntE, cntV, adjV, adjE);

    // ---- network ----
    k_lin<<<2048, 256, 0, stream>>>(x, W0, b0, hA, h0);

    for (int i = 0; i < NLAYER; ++i) {
        float beta = (float)log(0.5 / (double)(i + 1) + 1.0);
        k_edge_gather  <<<(N_E + 31) / 32, 256, 0, stream>>>(offE, adjV, factorE, hA, Xe);
        k_vertex_update<<<(N_V + 31) / 32, 256, 0, stream>>>(offV, adjE, Xe, degV, h0,
                                                             Ws + (size_t)i * NHID * NHID,
                                                             beta, hA);
    }
    k_out<<<4096, 256, 0, stream>>>(hA, Wout, bout, out);
}

// Round 12
// 1076.612 us; speedup vs baseline: 1.1494x; 1.0944x over previous
//
#include <hip/hip_runtime.h>
#include <math.h>

#define N_V    100000
#define N_E    200000
#define NNZ_C  1600000
#define NFEAT  128
#define NHID   64
#define NCLASS 40
#define NLAYER 8
#define ALPHA  0.1f

#define NWIN   8                 // one window per XCD (blockIdx&7 round-robin)
#define WE     (N_E / NWIN)      // 25000 edges per window
#define WV     (N_V / NWIN)      // 12500 vertices per window

#define MAXDE  48                // scratch stride, edge lists  (Poisson(8):  P(>48) ~ 1e-24)
#define MAXDV  64                // scratch stride, vertex lists (Poisson(16): P(>64) ~ 1e-19)

typedef _Float16 f16;
typedef _Float16 f16x8 __attribute__((ext_vector_type(8)));   // 16 B per lane

// ---------------------------------------------------------------------------
// ONE-PASS count+place, E side, XCD-affine windowed: p = atomicAdd(cntE[e])
// is simultaneously the histogram AND the slot. Replaces count2+scan+fill.
// Window w handled only by blocks with blockIdx&7==w -> that window's 4.8 MB
// scratch slice stays L2-resident so the 4 B stores merge before writeback.
__global__ __launch_bounds__(256) void k_place_e(const int* __restrict__ vertex,
                                                 const int* __restrict__ edges,
                                                 int* __restrict__ cntE,
                                                 int* __restrict__ scrE) {
    const int win  = blockIdx.x & (NWIN - 1);
    const int blk  = blockIdx.x >> 3;
    const int nblk = gridDim.x >> 3;
    const int eLo = win * WE, eHi = eLo + WE;
    for (int z = blk * blockDim.x + threadIdx.x; z < NNZ_C; z += nblk * blockDim.x) {
        int e = __builtin_nontemporal_load(&edges[z]);
        if (e >= eLo && e < eHi) {
            int v = vertex[z];
            int p = atomicAdd(&cntE[e], 1);
            if (p < MAXDE) scrE[e * MAXDE + p] = v;   // never triggers; safety
        }
    }
}

// ONE-PASS count+place, V side.
__global__ __launch_bounds__(256) void k_place_v(const int* __restrict__ vertex,
                                                 const int* __restrict__ edges,
                                                 int* __restrict__ cntV,
                                                 int* __restrict__ scrV) {
    const int win  = blockIdx.x & (NWIN - 1);
    const int blk  = blockIdx.x >> 3;
    const int nblk = gridDim.x >> 3;
    const int vLo = win * WV, vHi = vLo + WV;
    for (int z = blk * blockDim.x + threadIdx.x; z < NNZ_C; z += nblk * blockDim.x) {
        int v = __builtin_nontemporal_load(&vertex[z]);
        if (v >= vLo && v < vHi) {
            int e = edges[z];
            int p = atomicAdd(&cntV[v], 1);
            if (p < MAXDV) scrV[v * MAXDV + p] = e;
        }
    }
}

// factorE = degE / count (scatter-mean denom folded with degE)
__global__ __launch_bounds__(256) void k_factor(const int* __restrict__ cntE,
                                                const float* __restrict__ degE,
                                                float* __restrict__ factorE) {
    int e = blockIdx.x * blockDim.x + threadIdx.x;
    if (e < N_E) {
        int c = cntE[e];
        factorE[e] = (c > 0) ? degE[e] / (float)c : 0.0f;
    }
}

// h = relu(x @ W0 + b0) -> fp16; also copy to h0. One wave per row, lane = feature.
__global__ __launch_bounds__(256) void k_lin(const float* __restrict__ x,
                                             const float* __restrict__ W0,
                                             const float* __restrict__ b0,
                                             f16* __restrict__ h,
                                             f16* __restrict__ h0) {
    __shared__ float sW[NFEAT * NHID];   // 32 KB
    __shared__ float sb[NHID];
    for (int i = threadIdx.x; i < NFEAT * NHID; i += blockDim.x) sW[i] = W0[i];
    if (threadIdx.x < NHID) sb[threadIdx.x] = b0[threadIdx.x];
    __syncthreads();
    const int wid = threadIdx.x >> 6;
    const int f   = threadIdx.x & 63;
    const int wpb = blockDim.x >> 6;
    for (int n = blockIdx.x * wpb + wid; n < N_V; n += gridDim.x * wpb) {
        const float* xr = x + (size_t)n * NFEAT;
        float acc = sb[f];
        #pragma unroll 8
        for (int k = 0; k < NFEAT; ++k) acc = fmaf(xr[k], sW[k * NHID + f], acc);
        f16 r = (f16)fmaxf(acc, 0.0f);
        h [(size_t)n * NHID + f] = r;
        h0[(size_t)n * NHID + f] = r;
    }
}

// Xe[e] = (sum over incident vertices of h[v]) * factorE[e]
// 8-lane-subgroup-per-edge, 4-deep masked batch; indices come from the
// strided scratch row as ONE int4 load (16 B-aligned, always in-row).
__global__ __launch_bounds__(256) void k_edge_gather(const int* __restrict__ cntE,
                                                     const int* __restrict__ scrE,
                                                     const float* __restrict__ factorE,
                                                     const f16* __restrict__ h,
                                                     f16* __restrict__ Xe) {
    const int lane = threadIdx.x & 63;
    const int sg = lane >> 3, t = lane & 7;
    const int e = (blockIdx.x * 4 + (threadIdx.x >> 6)) * 8 + sg;  // 32 edges/block
    if (e >= N_E) return;
    const f16x8* __restrict__ hv = (const f16x8*)h;
    const int cnt = min(cntE[e], MAXDE);
    const int base = e * MAXDE;
    const float fac = factorE[e];
    float acc[8] = {0.f, 0.f, 0.f, 0.f, 0.f, 0.f, 0.f, 0.f};
    for (int w = 0; w < cnt; w += 4) {
        int4 q = *(const int4*)&scrE[base + w];     // slots w..w+3 (w<cnt => q.x valid)
        int i0 = q.x;
        int i1 = (w + 1 < cnt) ? q.y : q.x;         // clamp garbage slots to a valid idx
        int i2 = (w + 2 < cnt) ? q.z : q.x;
        int i3 = (w + 3 < cnt) ? q.w : q.x;
        float m1 = (w + 1 < cnt) ? 1.f : 0.f;
        float m2 = (w + 2 < cnt) ? 1.f : 0.f;
        float m3 = (w + 3 < cnt) ? 1.f : 0.f;
        f16x8 v0 = hv[(size_t)i0 * 8 + t];
        f16x8 v1 = hv[(size_t)i1 * 8 + t];
        f16x8 v2 = hv[(size_t)i2 * 8 + t];
        f16x8 v3 = hv[(size_t)i3 * 8 + t];
        #pragma unroll
        for (int j = 0; j < 8; ++j) {
            acc[j] += (float)v0[j];
            acc[j] = fmaf(m1, (float)v1[j], acc[j]);
            acc[j] = fmaf(m2, (float)v2[j], acc[j]);
            acc[j] = fmaf(m3, (float)v3[j], acc[j]);
        }
    }
    f16x8 o;
    #pragma unroll
    for (int j = 0; j < 8; ++j) o[j] = (f16)(acc[j] * fac);
    ((f16x8*)Xe)[(size_t)e * 8 + t] = o;
}

// Fused: Xv = (sum over incident edges of Xe[e]) * degV  ->  L2 rownorm ->
// GCNII mix -> 64x64 GEMM -> relu -> fp16. 8-lane-subgroup-per-vertex,
// 8-deep masked batch; indices via two int4 loads per batch.
__global__ __launch_bounds__(256) void k_vertex_update(const int* __restrict__ cntV,
                                                       const int* __restrict__ scrV,
                                                       const f16* __restrict__ Xe,
                                                       const float* __restrict__ degV,
                                                       const f16* __restrict__ h0,
                                                       const float* __restrict__ Wi,
                                                       float beta,
                                                       f16* __restrict__ h) {
    __shared__ float sW[NHID * NHID];    // 16 KB, row-major [k][f]
    for (int i = threadIdx.x; i < NHID * NHID; i += blockDim.x) sW[i] = Wi[i];
    __syncthreads();
    const int lane = threadIdx.x & 63;
    const int sg = lane >> 3, t = lane & 7;
    const int n = (blockIdx.x * 4 + (threadIdx.x >> 6)) * 8 + sg; // 32 verts/block
    if (n >= N_V) return;
    const f16x8* __restrict__ xe = (const f16x8*)Xe;
    const int cnt = min(cntV[n], MAXDV);
    const int base = n * MAXDV;
    const float dv = degV[n];
    const f16x8 h0v = ((const f16x8*)h0)[(size_t)n * 8 + t];
    float acc[8] = {0.f, 0.f, 0.f, 0.f, 0.f, 0.f, 0.f, 0.f};
    for (int w = 0; w < cnt; w += 8) {
        int4 qa = *(const int4*)&scrV[base + w];        // w multiple of 8 -> aligned
        int4 qb = *(const int4*)&scrV[base + w + 4];    // always in-row (w+7 <= 63)
        int   idx[8];
        float msk[8];
        idx[0] = qa.x;                       msk[0] = 1.f;   // w<cnt guaranteed
        idx[1] = (w + 1 < cnt) ? qa.y : qa.x; msk[1] = (w + 1 < cnt) ? 1.f : 0.f;
        idx[2] = (w + 2 < cnt) ? qa.z : qa.x; msk[2] = (w + 2 < cnt) ? 1.f : 0.f;
        idx[3] = (w + 3 < cnt) ? qa.w : qa.x; msk[3] = (w + 3 < cnt) ? 1.f : 0.f;
        idx[4] = (w + 4 < cnt) ? qb.x : qa.x; msk[4] = (w + 4 < cnt) ? 1.f : 0.f;
        idx[5] = (w + 5 < cnt) ? qb.y : qa.x; msk[5] = (w + 5 < cnt) ? 1.f : 0.f;
        idx[6] = (w + 6 < cnt) ? qb.z : qa.x; msk[6] = (w + 6 < cnt) ? 1.f : 0.f;
        idx[7] = (w + 7 < cnt) ? qb.w : qa.x; msk[7] = (w + 7 < cnt) ? 1.f : 0.f;
        f16x8 v[8];
        #pragma unroll
        for (int r = 0; r < 8; ++r) v[r] = xe[(size_t)idx[r] * 8 + t];
        #pragma unroll
        for (int j = 0; j < 8; ++j) {
            #pragma unroll
            for (int r = 0; r < 8; ++r)
                acc[j] = fmaf(msk[r], (float)v[r][j], acc[j]);
        }
    }
    // scale by degV FIRST, then norm of the scaled row (matches reference)
    float xv[8], ss = 0.f;
    #pragma unroll
    for (int j = 0; j < 8; ++j) { xv[j] = acc[j] * dv; ss = fmaf(xv[j], xv[j], ss); }
    #pragma unroll
    for (int off = 1; off <= 4; off <<= 1)   // reduce within the 8-lane subgroup
        ss += __shfl_xor(ss, off, 64);
    float rn  = sqrtf(ss);
    float inv = (rn > 0.0f) ? 1.0f / rn : 0.0f;
    float xi[8];
    #pragma unroll
    for (int j = 0; j < 8; ++j)
        xi[j] = (1.0f - ALPHA) * (xv[j] * inv) + ALPHA * (float)h0v[j];
    // y_f = sum_k xi_k * W[k][f], f = 8t+j; xi_k owned by lane 8*sg+(k>>3),
    // component k&7. Uniform k-loop; LDS float4 reads are 2-way alias (free).
    float y[8] = {0.f, 0.f, 0.f, 0.f, 0.f, 0.f, 0.f, 0.f};
    #pragma unroll
    for (int k = 0; k < NHID; ++k) {
        float xk = __shfl(xi[k & 7], 8 * sg + (k >> 3), 64);
        const float4 wa = *(const float4*)&sW[k * NHID + 8 * t];
        const float4 wb = *(const float4*)&sW[k * NHID + 8 * t + 4];
        y[0] = fmaf(xk, wa.x, y[0]);
        y[1] = fmaf(xk, wa.y, y[1]);
        y[2] = fmaf(xk, wa.z, y[2]);
        y[3] = fmaf(xk, wa.w, y[3]);
        y[4] = fmaf(xk, wb.x, y[4]);
        y[5] = fmaf(xk, wb.y, y[5]);
        y[6] = fmaf(xk, wb.z, y[6]);
        y[7] = fmaf(xk, wb.w, y[7]);
    }
    f16x8 o;
    #pragma unroll
    for (int j = 0; j < 8; ++j) {
        float v = fmaf(beta, y[j] - xi[j], xi[j]);   // (1-b)*xi + b*y
        o[j] = (f16)fmaxf(v, 0.0f);
    }
    ((f16x8*)h)[(size_t)n * 8 + t] = o;
}

// out = h @ Wout + bout. One wave per row; lanes 0..39 hold the classes.
__global__ __launch_bounds__(256) void k_out(const f16* __restrict__ h,
                                             const float* __restrict__ Wout,
                                             const float* __restrict__ bout,
                                             float* __restrict__ out) {
    __shared__ float sW[NHID * NCLASS];  // 10 KB
    __shared__ float sb[NCLASS];
    for (int i = threadIdx.x; i < NHID * NCLASS; i += blockDim.x) sW[i] = Wout[i];
    if (threadIdx.x < NCLASS) sb[threadIdx.x] = bout[threadIdx.x];
    __syncthreads();
    const int wid = threadIdx.x >> 6;
    const int f   = threadIdx.x & 63;
    const int wpb = blockDim.x >> 6;
    const int c   = (f < NCLASS) ? f : 0;
    for (int n = blockIdx.x * wpb + wid; n < N_V; n += gridDim.x * wpb) {
        float hv = (float)h[(size_t)n * NHID + f];
        float y  = sb[c];
        #pragma unroll 8
        for (int k = 0; k < NHID; ++k)
            y = fmaf(__shfl(hv, k, 64), sW[k * NCLASS + c], y);
        if (f < NCLASS) out[(size_t)n * NCLASS + f] = y;
    }
}

// ---------------------------------------------------------------------------
extern "C" void kernel_launch(void* const* d_in, const int* in_sizes, int n_in,
                              void* d_out, int out_size, void* d_ws, size_t ws_size,
                              hipStream_t stream) {
    const float* x      = (const float*)d_in[0];
    const int*   vertex = (const int*)  d_in[1];
    const int*   edges  = (const int*)  d_in[2];
    const float* degE   = (const float*)d_in[3];
    const float* degV   = (const float*)d_in[4];
    const float* W0     = (const float*)d_in[5];
    const float* b0     = (const float*)d_in[6];
    const float* Ws     = (const float*)d_in[7];
    const float* Wout   = (const float*)d_in[8];
    const float* bout   = (const float*)d_in[9];
    float* out = (float*)d_out;

    // workspace carve-up (~117 MB)
    char* p = (char*)d_ws;
    auto carve = [&](size_t bytes) { char* r = p; p += (bytes + 255) & ~(size_t)255; return r; };
    f16*   h0      = (f16*)  carve((size_t)N_V * NHID * sizeof(f16));    // 12.8 MB
    f16*   hA      = (f16*)  carve((size_t)N_V * NHID * sizeof(f16));    // 12.8 MB
    f16*   Xe      = (f16*)  carve((size_t)N_E * NHID * sizeof(f16));    // 25.6 MB
    float* factorE = (float*)carve((size_t)N_E * sizeof(float));         //  0.8 MB
    int*   cntE    = (int*)  carve((size_t)N_E * sizeof(int));           //  0.8 MB
    int*   cntV    = (int*)  carve((size_t)N_V * sizeof(int));           //  0.4 MB (contiguous after cntE)
    int*   scrE    = (int*)  carve((size_t)N_E * MAXDE * sizeof(int));   // 38.4 MB
    int*   scrV    = (int*)  carve((size_t)N_V * MAXDV * sizeof(int));   // 25.6 MB

    // ---- one-pass adjacency build (per call) ----
    // N_E*4 = 800000 B is 256-aligned, so cntV directly follows cntE:
    hipMemsetAsync(cntE, 0, (size_t)(N_E + N_V) * sizeof(int), stream);
    k_place_e<<<NWIN * 256, 256, 0, stream>>>(vertex, edges, cntE, scrE);
    k_place_v<<<NWIN * 256, 256, 0, stream>>>(vertex, edges, cntV, scrV);
    k_factor <<<(N_E + 255) / 256, 256, 0, stream>>>(cntE, degE, factorE);

    // ---- network ----
    k_lin<<<2048, 256, 0, stream>>>(x, W0, b0, hA, h0);

    for (int i = 0; i < NLAYER; ++i) {
        float beta = (float)log(0.5 / (double)(i + 1) + 1.0);
        k_edge_gather  <<<(N_E + 31) / 32, 256, 0, stream>>>(cntE, scrE, factorE, hA, Xe);
        k_vertex_update<<<(N_V + 31) / 32, 256, 0, stream>>>(cntV, scrV, Xe, degV, h0,
                                                             Ws + (size_t)i * NHID * NHID,
                                                             beta, hA);
    }
    k_out<<<4096, 256, 0, stream>>>(hA, Wout, bout, out);
}

// Round 13
// 1005.544 us; speedup vs baseline: 1.2306x; 1.0707x over previous
//
#include <hip/hip_runtime.h>
#include <math.h>

#define N_V    100000
#define N_E    200000
#define NNZ_C  1600000
#define NFEAT  128
#define NHID   64
#define NCLASS 40
#define NLAYER 8
#define ALPHA  0.1f

#define NWIN   8                 // one window per XCD (blockIdx&7 round-robin)
#define WE     (N_E / NWIN)      // 25000 edges per window
#define WV     (N_V / NWIN)      // 12500 vertices per window

#define MAXDE  48                // scratch stride, edge lists  (Poisson(8):  P(>48) ~ 1e-24)
#define MAXDV  64                // scratch stride, vertex lists (Poisson(16): P(>64) ~ 1e-19)

typedef _Float16 f16;
typedef _Float16 f16x8 __attribute__((ext_vector_type(8)));   // 16 B per lane

// ---------------------------------------------------------------------------
// ONE-PASS count+place, E side, XCD-affine windowed: p = atomicAdd(cntE[e])
// is simultaneously the histogram AND the slot. (verified round 12)
__global__ __launch_bounds__(256) void k_place_e(const int* __restrict__ vertex,
                                                 const int* __restrict__ edges,
                                                 int* __restrict__ cntE,
                                                 int* __restrict__ scrE) {
    const int win  = blockIdx.x & (NWIN - 1);
    const int blk  = blockIdx.x >> 3;
    const int nblk = gridDim.x >> 3;
    const int eLo = win * WE, eHi = eLo + WE;
    for (int z = blk * blockDim.x + threadIdx.x; z < NNZ_C; z += nblk * blockDim.x) {
        int e = __builtin_nontemporal_load(&edges[z]);
        if (e >= eLo && e < eHi) {
            int v = vertex[z];
            int p = atomicAdd(&cntE[e], 1);
            if (p < MAXDE) scrE[e * MAXDE + p] = v;   // never triggers; safety
        }
    }
}

// ONE-PASS count+place, V side.
__global__ __launch_bounds__(256) void k_place_v(const int* __restrict__ vertex,
                                                 const int* __restrict__ edges,
                                                 int* __restrict__ cntV,
                                                 int* __restrict__ scrV) {
    const int win  = blockIdx.x & (NWIN - 1);
    const int blk  = blockIdx.x >> 3;
    const int nblk = gridDim.x >> 3;
    const int vLo = win * WV, vHi = vLo + WV;
    for (int z = blk * blockDim.x + threadIdx.x; z < NNZ_C; z += nblk * blockDim.x) {
        int v = __builtin_nontemporal_load(&vertex[z]);
        if (v >= vLo && v < vHi) {
            int e = edges[z];
            int p = atomicAdd(&cntV[v], 1);
            if (p < MAXDV) scrV[v * MAXDV + p] = e;
        }
    }
}

// factorE = degE / count (scatter-mean denom folded with degE)
__global__ __launch_bounds__(256) void k_factor(const int* __restrict__ cntE,
                                                const float* __restrict__ degE,
                                                float* __restrict__ factorE) {
    int e = blockIdx.x * blockDim.x + threadIdx.x;
    if (e < N_E) {
        int c = cntE[e];
        factorE[e] = (c > 0) ? degE[e] / (float)c : 0.0f;
    }
}

// h = relu(x @ W0 + b0) -> fp16; also copy to h0.
// REWRITE (round 13): 8-lane subgroup per ROW PAIR. Lane t holds
// x[r][16t..16t+15] in 16 registers (4x coalesced float4). k-loop fully
// unrolled: 1 shuffle broadcasts x_k, W row read as 2x ds_read_b128
// (8-way subgroup broadcast = free), 16 independent FMA chains.
// Kills the old per-row 32KB W re-read (3.2 GB LDS traffic -> 200 MB)
// and the 128-deep serial acc chain + scalar uniform loads.
__global__ __launch_bounds__(256) void k_lin(const float* __restrict__ x,
                                             const float* __restrict__ W0,
                                             const float* __restrict__ b0,
                                             f16* __restrict__ h,
                                             f16* __restrict__ h0) {
    __shared__ float sW[NFEAT * NHID];   // 32 KB, row-major [k][f]
    __shared__ float sb[NHID];
    for (int i = threadIdx.x; i < NFEAT * NHID; i += blockDim.x) sW[i] = W0[i];
    if (threadIdx.x < NHID) sb[threadIdx.x] = b0[threadIdx.x];
    __syncthreads();
    const int lane = threadIdx.x & 63;
    const int t    = lane & 7;
    const int pair = blockIdx.x * 32 + (threadIdx.x >> 3);   // 32 subgroups/block
    if (pair >= N_V / 2) return;                              // N_V even
    const int r0 = 2 * pair, r1 = r0 + 1;
    const float4* __restrict__ x4 = (const float4*)x;         // 32 float4 per row
    // register-stage both rows' slices (explicit components -> stays in VGPRs)
    float xr0[16], xr1[16];
    #pragma unroll
    for (int i = 0; i < 4; ++i) {
        float4 q0 = x4[(size_t)r0 * 32 + t * 4 + i];
        float4 q1 = x4[(size_t)r1 * 32 + t * 4 + i];
        xr0[4 * i + 0] = q0.x; xr0[4 * i + 1] = q0.y;
        xr0[4 * i + 2] = q0.z; xr0[4 * i + 3] = q0.w;
        xr1[4 * i + 0] = q1.x; xr1[4 * i + 1] = q1.y;
        xr1[4 * i + 2] = q1.z; xr1[4 * i + 3] = q1.w;
    }
    // acc init = bias (f = 8t+j)
    float a0[8], a1[8];
    #pragma unroll
    for (int j = 0; j < 8; ++j) { a0[j] = sb[8 * t + j]; a1[j] = a0[j]; }
    const int sgbase = lane & 56;        // subgroup base lane within wave
    #pragma unroll
    for (int k = 0; k < NFEAT; ++k) {
        // owner lane of x_k within the subgroup: t_owner = k>>4, comp k&15
        float xk0 = __shfl(xr0[k & 15], sgbase | (k >> 4), 64);
        float xk1 = __shfl(xr1[k & 15], sgbase | (k >> 4), 64);
        const float4 wa = *(const float4*)&sW[k * NHID + 8 * t];
        const float4 wb = *(const float4*)&sW[k * NHID + 8 * t + 4];
        a0[0] = fmaf(xk0, wa.x, a0[0]);  a1[0] = fmaf(xk1, wa.x, a1[0]);
        a0[1] = fmaf(xk0, wa.y, a0[1]);  a1[1] = fmaf(xk1, wa.y, a1[1]);
        a0[2] = fmaf(xk0, wa.z, a0[2]);  a1[2] = fmaf(xk1, wa.z, a1[2]);
        a0[3] = fmaf(xk0, wa.w, a0[3]);  a1[3] = fmaf(xk1, wa.w, a1[3]);
        a0[4] = fmaf(xk0, wb.x, a0[4]);  a1[4] = fmaf(xk1, wb.x, a1[4]);
        a0[5] = fmaf(xk0, wb.y, a0[5]);  a1[5] = fmaf(xk1, wb.y, a1[5]);
        a0[6] = fmaf(xk0, wb.z, a0[6]);  a1[6] = fmaf(xk1, wb.z, a1[6]);
        a0[7] = fmaf(xk0, wb.w, a0[7]);  a1[7] = fmaf(xk1, wb.w, a1[7]);
    }
    f16x8 o0, o1;
    #pragma unroll
    for (int j = 0; j < 8; ++j) {
        o0[j] = (f16)fmaxf(a0[j], 0.0f);
        o1[j] = (f16)fmaxf(a1[j], 0.0f);
    }
    ((f16x8*)h )[(size_t)r0 * 8 + t] = o0;
    ((f16x8*)h )[(size_t)r1 * 8 + t] = o1;
    ((f16x8*)h0)[(size_t)r0 * 8 + t] = o0;
    ((f16x8*)h0)[(size_t)r1 * 8 + t] = o1;
}

// Xe[e] = (sum over incident vertices of h[v]) * factorE[e]
// 8-lane-subgroup-per-edge, 4-deep masked batch; indices come from the
// strided scratch row as ONE int4 load (16 B-aligned, always in-row).
__global__ __launch_bounds__(256) void k_edge_gather(const int* __restrict__ cntE,
                                                     const int* __restrict__ scrE,
                                                     const float* __restrict__ factorE,
                                                     const f16* __restrict__ h,
                                                     f16* __restrict__ Xe) {
    const int lane = threadIdx.x & 63;
    const int sg = lane >> 3, t = lane & 7;
    const int e = (blockIdx.x * 4 + (threadIdx.x >> 6)) * 8 + sg;  // 32 edges/block
    if (e >= N_E) return;
    const f16x8* __restrict__ hv = (const f16x8*)h;
    const int cnt = min(cntE[e], MAXDE);
    const int base = e * MAXDE;
    const float fac = factorE[e];
    float acc[8] = {0.f, 0.f, 0.f, 0.f, 0.f, 0.f, 0.f, 0.f};
    for (int w = 0; w < cnt; w += 4) {
        int4 q = *(const int4*)&scrE[base + w];     // slots w..w+3 (w<cnt => q.x valid)
        int i0 = q.x;
        int i1 = (w + 1 < cnt) ? q.y : q.x;         // clamp garbage slots to a valid idx
        int i2 = (w + 2 < cnt) ? q.z : q.x;
        int i3 = (w + 3 < cnt) ? q.w : q.x;
        float m1 = (w + 1 < cnt) ? 1.f : 0.f;
        float m2 = (w + 2 < cnt) ? 1.f : 0.f;
        float m3 = (w + 3 < cnt) ? 1.f : 0.f;
        f16x8 v0 = hv[(size_t)i0 * 8 + t];
        f16x8 v1 = hv[(size_t)i1 * 8 + t];
        f16x8 v2 = hv[(size_t)i2 * 8 + t];
        f16x8 v3 = hv[(size_t)i3 * 8 + t];
        #pragma unroll
        for (int j = 0; j < 8; ++j) {
            acc[j] += (float)v0[j];
            acc[j] = fmaf(m1, (float)v1[j], acc[j]);
            acc[j] = fmaf(m2, (float)v2[j], acc[j]);
            acc[j] = fmaf(m3, (float)v3[j], acc[j]);
        }
    }
    f16x8 o;
    #pragma unroll
    for (int j = 0; j < 8; ++j) o[j] = (f16)(acc[j] * fac);
    ((f16x8*)Xe)[(size_t)e * 8 + t] = o;
}

// Fused: Xv = (sum over incident edges of Xe[e]) * degV  ->  L2 rownorm ->
// GCNII mix -> 64x64 GEMM -> relu -> fp16. 8-lane-subgroup-per-vertex,
// 8-deep masked batch; indices via two int4 loads per batch.
__global__ __launch_bounds__(256) void k_vertex_update(const int* __restrict__ cntV,
                                                       const int* __restrict__ scrV,
                                                       const f16* __restrict__ Xe,
                                                       const float* __restrict__ degV,
                                                       const f16* __restrict__ h0,
                                                       const float* __restrict__ Wi,
                                                       float beta,
                                                       f16* __restrict__ h) {
    __shared__ float sW[NHID * NHID];    // 16 KB, row-major [k][f]
    for (int i = threadIdx.x; i < NHID * NHID; i += blockDim.x) sW[i] = Wi[i];
    __syncthreads();
    const int lane = threadIdx.x & 63;
    const int sg = lane >> 3, t = lane & 7;
    const int n = (blockIdx.x * 4 + (threadIdx.x >> 6)) * 8 + sg; // 32 verts/block
    if (n >= N_V) return;
    const f16x8* __restrict__ xe = (const f16x8*)Xe;
    const int cnt = min(cntV[n], MAXDV);
    const int base = n * MAXDV;
    const float dv = degV[n];
    const f16x8 h0v = ((const f16x8*)h0)[(size_t)n * 8 + t];
    float acc[8] = {0.f, 0.f, 0.f, 0.f, 0.f, 0.f, 0.f, 0.f};
    for (int w = 0; w < cnt; w += 8) {
        int4 qa = *(const int4*)&scrV[base + w];        // w multiple of 8 -> aligned
        int4 qb = *(const int4*)&scrV[base + w + 4];    // always in-row (w+7 <= 63)
        int   idx[8];
        float msk[8];
        idx[0] = qa.x;                       msk[0] = 1.f;   // w<cnt guaranteed
        idx[1] = (w + 1 < cnt) ? qa.y : qa.x; msk[1] = (w + 1 < cnt) ? 1.f : 0.f;
        idx[2] = (w + 2 < cnt) ? qa.z : qa.x; msk[2] = (w + 2 < cnt) ? 1.f : 0.f;
        idx[3] = (w + 3 < cnt) ? qa.w : qa.x; msk[3] = (w + 3 < cnt) ? 1.f : 0.f;
        idx[4] = (w + 4 < cnt) ? qb.x : qa.x; msk[4] = (w + 4 < cnt) ? 1.f : 0.f;
        idx[5] = (w + 5 < cnt) ? qb.y : qa.x; msk[5] = (w + 5 < cnt) ? 1.f : 0.f;
        idx[6] = (w + 6 < cnt) ? qb.z : qa.x; msk[6] = (w + 6 < cnt) ? 1.f : 0.f;
        idx[7] = (w + 7 < cnt) ? qb.w : qa.x; msk[7] = (w + 7 < cnt) ? 1.f : 0.f;
        f16x8 v[8];
        #pragma unroll
        for (int r = 0; r < 8; ++r) v[r] = xe[(size_t)idx[r] * 8 + t];
        #pragma unroll
        for (int j = 0; j < 8; ++j) {
            #pragma unroll
            for (int r = 0; r < 8; ++r)
                acc[j] = fmaf(msk[r], (float)v[r][j], acc[j]);
        }
    }
    // scale by degV FIRST, then norm of the scaled row (matches reference)
    float xv[8], ss = 0.f;
    #pragma unroll
    for (int j = 0; j < 8; ++j) { xv[j] = acc[j] * dv; ss = fmaf(xv[j], xv[j], ss); }
    #pragma unroll
    for (int off = 1; off <= 4; off <<= 1)   // reduce within the 8-lane subgroup
        ss += __shfl_xor(ss, off, 64);
    float rn  = sqrtf(ss);
    float inv = (rn > 0.0f) ? 1.0f / rn : 0.0f;
    float xi[8];
    #pragma unroll
    for (int j = 0; j < 8; ++j)
        xi[j] = (1.0f - ALPHA) * (xv[j] * inv) + ALPHA * (float)h0v[j];
    // y_f = sum_k xi_k * W[k][f], f = 8t+j; xi_k owned by lane 8*sg+(k>>3),
    // component k&7. Uniform k-loop; LDS float4 reads are 2-way alias (free).
    float y[8] = {0.f, 0.f, 0.f, 0.f, 0.f, 0.f, 0.f, 0.f};
    #pragma unroll
    for (int k = 0; k < NHID; ++k) {
        float xk = __shfl(xi[k & 7], 8 * sg + (k >> 3), 64);
        const float4 wa = *(const float4*)&sW[k * NHID + 8 * t];
        const float4 wb = *(const float4*)&sW[k * NHID + 8 * t + 4];
        y[0] = fmaf(xk, wa.x, y[0]);
        y[1] = fmaf(xk, wa.y, y[1]);
        y[2] = fmaf(xk, wa.z, y[2]);
        y[3] = fmaf(xk, wa.w, y[3]);
        y[4] = fmaf(xk, wb.x, y[4]);
        y[5] = fmaf(xk, wb.y, y[5]);
        y[6] = fmaf(xk, wb.z, y[6]);
        y[7] = fmaf(xk, wb.w, y[7]);
    }
    f16x8 o;
    #pragma unroll
    for (int j = 0; j < 8; ++j) {
        float v = fmaf(beta, y[j] - xi[j], xi[j]);   // (1-b)*xi + b*y
        o[j] = (f16)fmaxf(v, 0.0f);
    }
    ((f16x8*)h)[(size_t)n * 8 + t] = o;
}

// out = h @ Wout + bout. One wave per row; lanes 0..39 hold the classes.
__global__ __launch_bounds__(256) void k_out(const f16* __restrict__ h,
                                             const float* __restrict__ Wout,
                                             const float* __restrict__ bout,
                                             float* __restrict__ out) {
    __shared__ float sW[NHID * NCLASS];  // 10 KB
    __shared__ float sb[NCLASS];
    for (int i = threadIdx.x; i < NHID * NCLASS; i += blockDim.x) sW[i] = Wout[i];
    if (threadIdx.x < NCLASS) sb[threadIdx.x] = bout[threadIdx.x];
    __syncthreads();
    const int wid = threadIdx.x >> 6;
    const int f   = threadIdx.x & 63;
    const int wpb = blockDim.x >> 6;
    const int c   = (f < NCLASS) ? f : 0;
    for (int n = blockIdx.x * wpb + wid; n < N_V; n += gridDim.x * wpb) {
        float hv = (float)h[(size_t)n * NHID + f];
        float y  = sb[c];
        #pragma unroll 8
        for (int k = 0; k < NHID; ++k)
            y = fmaf(__shfl(hv, k, 64), sW[k * NCLASS + c], y);
        if (f < NCLASS) out[(size_t)n * NCLASS + f] = y;
    }
}

// ---------------------------------------------------------------------------
extern "C" void kernel_launch(void* const* d_in, const int* in_sizes, int n_in,
                              void* d_out, int out_size, void* d_ws, size_t ws_size,
                              hipStream_t stream) {
    const float* x      = (const float*)d_in[0];
    const int*   vertex = (const int*)  d_in[1];
    const int*   edges  = (const int*)  d_in[2];
    const float* degE   = (const float*)d_in[3];
    const float* degV   = (const float*)d_in[4];
    const float* W0     = (const float*)d_in[5];
    const float* b0     = (const float*)d_in[6];
    const float* Ws     = (const float*)d_in[7];
    const float* Wout   = (const float*)d_in[8];
    const float* bout   = (const float*)d_in[9];
    float* out = (float*)d_out;

    // workspace carve-up (~117 MB)
    char* p = (char*)d_ws;
    auto carve = [&](size_t bytes) { char* r = p; p += (bytes + 255) & ~(size_t)255; return r; };
    f16*   h0      = (f16*)  carve((size_t)N_V * NHID * sizeof(f16));    // 12.8 MB
    f16*   hA      = (f16*)  carve((size_t)N_V * NHID * sizeof(f16));    // 12.8 MB
    f16*   Xe      = (f16*)  carve((size_t)N_E * NHID * sizeof(f16));    // 25.6 MB
    float* factorE = (float*)carve((size_t)N_E * sizeof(float));         //  0.8 MB
    int*   cntE    = (int*)  carve((size_t)N_E * sizeof(int));           //  0.8 MB
    int*   cntV    = (int*)  carve((size_t)N_V * sizeof(int));           //  0.4 MB (contiguous after cntE)
    int*   scrE    = (int*)  carve((size_t)N_E * MAXDE * sizeof(int));   // 38.4 MB
    int*   scrV    = (int*)  carve((size_t)N_V * MAXDV * sizeof(int));   // 25.6 MB

    // ---- one-pass adjacency build (per call) ----
    // N_E*4 = 800000 B is 256-aligned, so cntV directly follows cntE:
    hipMemsetAsync(cntE, 0, (size_t)(N_E + N_V) * sizeof(int), stream);
    k_place_e<<<NWIN * 256, 256, 0, stream>>>(vertex, edges, cntE, scrE);
    k_place_v<<<NWIN * 256, 256, 0, stream>>>(vertex, edges, cntV, scrV);
    k_factor <<<(N_E + 255) / 256, 256, 0, stream>>>(cntE, degE, factorE);

    // ---- network ----
    k_lin<<<(N_V / 2 + 31) / 32, 256, 0, stream>>>(x, W0, b0, hA, h0);

    for (int i = 0; i < NLAYER; ++i) {
        float beta = (float)log(0.5 / (double)(i + 1) + 1.0);
        k_edge_gather  <<<(N_E + 31) / 32, 256, 0, stream>>>(cntE, scrE, factorE, hA, Xe);
        k_vertex_update<<<(N_V + 31) / 32, 256, 0, stream>>>(cntV, scrV, Xe, degV, h0,
                                                             Ws + (size_t)i * NHID * NHID,
                                                             beta, hA);
    }
    k_out<<<4096, 256, 0, stream>>>(hA, Wout, bout, out);
}

// Round 14
// 932.842 us; speedup vs baseline: 1.3265x; 1.0779x over previous
//
#include <hip/hip_runtime.h>
#include <math.h>

#define N_V    100000
#define N_E    200000
#define NNZ_C  1600000
#define NFEAT  128
#define NHID   64
#define NCLASS 40
#define NLAYER 8
#define ALPHA  0.1f

#define NWIN   8                 // one window per XCD (blockIdx&7 round-robin)
#define WE     (N_E / NWIN)      // 25000 edges per window
#define WV     (N_V / NWIN)      // 12500 vertices per window

#define MAXDE  48                // scratch stride, edge lists  (Poisson(8):  P(>48) ~ 1e-24)
#define MAXDV  64                // scratch stride, vertex lists (Poisson(16): P(>64) ~ 1e-19)

typedef _Float16 f16;
typedef _Float16 f16x8 __attribute__((ext_vector_type(8)));   // 16 B per lane

// ---------------------------------------------------------------------------
// ONE-PASS count+place, E side, XCD-affine windowed: p = atomicAdd(cntE[e])
// is simultaneously the histogram AND the slot. (verified round 12)
__global__ __launch_bounds__(256) void k_place_e(const int* __restrict__ vertex,
                                                 const int* __restrict__ edges,
                                                 int* __restrict__ cntE,
                                                 int* __restrict__ scrE) {
    const int win  = blockIdx.x & (NWIN - 1);
    const int blk  = blockIdx.x >> 3;
    const int nblk = gridDim.x >> 3;
    const int eLo = win * WE, eHi = eLo + WE;
    for (int z = blk * blockDim.x + threadIdx.x; z < NNZ_C; z += nblk * blockDim.x) {
        int e = __builtin_nontemporal_load(&edges[z]);
        if (e >= eLo && e < eHi) {
            int v = vertex[z];
            int p = atomicAdd(&cntE[e], 1);
            if (p < MAXDE) scrE[e * MAXDE + p] = v;   // never triggers; safety
        }
    }
}

// ONE-PASS count+place, V side.
__global__ __launch_bounds__(256) void k_place_v(const int* __restrict__ vertex,
                                                 const int* __restrict__ edges,
                                                 int* __restrict__ cntV,
                                                 int* __restrict__ scrV) {
    const int win  = blockIdx.x & (NWIN - 1);
    const int blk  = blockIdx.x >> 3;
    const int nblk = gridDim.x >> 3;
    const int vLo = win * WV, vHi = vLo + WV;
    for (int z = blk * blockDim.x + threadIdx.x; z < NNZ_C; z += nblk * blockDim.x) {
        int v = __builtin_nontemporal_load(&vertex[z]);
        if (v >= vLo && v < vHi) {
            int e = edges[z];
            int p = atomicAdd(&cntV[v], 1);
            if (p < MAXDV) scrV[v * MAXDV + p] = e;
        }
    }
}

// factorE = degE / count (scatter-mean denom folded with degE)
__global__ __launch_bounds__(256) void k_factor(const int* __restrict__ cntE,
                                                const float* __restrict__ degE,
                                                float* __restrict__ factorE) {
    int e = blockIdx.x * blockDim.x + threadIdx.x;
    if (e < N_E) {
        int c = cntE[e];
        factorE[e] = (c > 0) ? degE[e] / (float)c : 0.0f;
    }
}

// h = relu(x @ W0 + b0) -> fp16; also copy to h0. (verified round 13)
// 8-lane subgroup per ROW PAIR; W row read shared 8-way; 16 indep FMA chains.
__global__ __launch_bounds__(256) void k_lin(const float* __restrict__ x,
                                             const float* __restrict__ W0,
                                             const float* __restrict__ b0,
                                             f16* __restrict__ h,
                                             f16* __restrict__ h0) {
    __shared__ float sW[NFEAT * NHID];   // 32 KB, row-major [k][f]
    __shared__ float sb[NHID];
    for (int i = threadIdx.x; i < NFEAT * NHID; i += blockDim.x) sW[i] = W0[i];
    if (threadIdx.x < NHID) sb[threadIdx.x] = b0[threadIdx.x];
    __syncthreads();
    const int lane = threadIdx.x & 63;
    const int t    = lane & 7;
    const int pair = blockIdx.x * 32 + (threadIdx.x >> 3);   // 32 subgroups/block
    if (pair >= N_V / 2) return;                              // N_V even
    const int r0 = 2 * pair, r1 = r0 + 1;
    const float4* __restrict__ x4 = (const float4*)x;         // 32 float4 per row
    float xr0[16], xr1[16];
    #pragma unroll
    for (int i = 0; i < 4; ++i) {
        float4 q0 = x4[(size_t)r0 * 32 + t * 4 + i];
        float4 q1 = x4[(size_t)r1 * 32 + t * 4 + i];
        xr0[4 * i + 0] = q0.x; xr0[4 * i + 1] = q0.y;
        xr0[4 * i + 2] = q0.z; xr0[4 * i + 3] = q0.w;
        xr1[4 * i + 0] = q1.x; xr1[4 * i + 1] = q1.y;
        xr1[4 * i + 2] = q1.z; xr1[4 * i + 3] = q1.w;
    }
    float a0[8], a1[8];
    #pragma unroll
    for (int j = 0; j < 8; ++j) { a0[j] = sb[8 * t + j]; a1[j] = a0[j]; }
    const int sgbase = lane & 56;        // subgroup base lane within wave
    #pragma unroll
    for (int k = 0; k < NFEAT; ++k) {
        float xk0 = __shfl(xr0[k & 15], sgbase | (k >> 4), 64);
        float xk1 = __shfl(xr1[k & 15], sgbase | (k >> 4), 64);
        const float4 wa = *(const float4*)&sW[k * NHID + 8 * t];
        const float4 wb = *(const float4*)&sW[k * NHID + 8 * t + 4];
        a0[0] = fmaf(xk0, wa.x, a0[0]);  a1[0] = fmaf(xk1, wa.x, a1[0]);
        a0[1] = fmaf(xk0, wa.y, a0[1]);  a1[1] = fmaf(xk1, wa.y, a1[1]);
        a0[2] = fmaf(xk0, wa.z, a0[2]);  a1[2] = fmaf(xk1, wa.z, a1[2]);
        a0[3] = fmaf(xk0, wa.w, a0[3]);  a1[3] = fmaf(xk1, wa.w, a1[3]);
        a0[4] = fmaf(xk0, wb.x, a0[4]);  a1[4] = fmaf(xk1, wb.x, a1[4]);
        a0[5] = fmaf(xk0, wb.y, a0[5]);  a1[5] = fmaf(xk1, wb.y, a1[5]);
        a0[6] = fmaf(xk0, wb.z, a0[6]);  a1[6] = fmaf(xk1, wb.z, a1[6]);
        a0[7] = fmaf(xk0, wb.w, a0[7]);  a1[7] = fmaf(xk1, wb.w, a1[7]);
    }
    f16x8 o0, o1;
    #pragma unroll
    for (int j = 0; j < 8; ++j) {
        o0[j] = (f16)fmaxf(a0[j], 0.0f);
        o1[j] = (f16)fmaxf(a1[j], 0.0f);
    }
    ((f16x8*)h )[(size_t)r0 * 8 + t] = o0;
    ((f16x8*)h )[(size_t)r1 * 8 + t] = o1;
    ((f16x8*)h0)[(size_t)r0 * 8 + t] = o0;
    ((f16x8*)h0)[(size_t)r1 * 8 + t] = o1;
}

// Xe[e] = (sum over incident vertices of h[v]) * factorE[e]
// 8-lane-subgroup-per-edge, 4-deep masked batch; indices come from the
// strided scratch row as ONE int4 load (16 B-aligned, always in-row).
__global__ __launch_bounds__(256) void k_edge_gather(const int* __restrict__ cntE,
                                                     const int* __restrict__ scrE,
                                                     const float* __restrict__ factorE,
                                                     const f16* __restrict__ h,
                                                     f16* __restrict__ Xe) {
    const int lane = threadIdx.x & 63;
    const int sg = lane >> 3, t = lane & 7;
    const int e = (blockIdx.x * 4 + (threadIdx.x >> 6)) * 8 + sg;  // 32 edges/block
    if (e >= N_E) return;
    const f16x8* __restrict__ hv = (const f16x8*)h;
    const int cnt = min(cntE[e], MAXDE);
    const int base = e * MAXDE;
    const float fac = factorE[e];
    float acc[8] = {0.f, 0.f, 0.f, 0.f, 0.f, 0.f, 0.f, 0.f};
    for (int w = 0; w < cnt; w += 4) {
        int4 q = *(const int4*)&scrE[base + w];     // slots w..w+3 (w<cnt => q.x valid)
        int i0 = q.x;
        int i1 = (w + 1 < cnt) ? q.y : q.x;         // clamp garbage slots to a valid idx
        int i2 = (w + 2 < cnt) ? q.z : q.x;
        int i3 = (w + 3 < cnt) ? q.w : q.x;
        float m1 = (w + 1 < cnt) ? 1.f : 0.f;
        float m2 = (w + 2 < cnt) ? 1.f : 0.f;
        float m3 = (w + 3 < cnt) ? 1.f : 0.f;
        f16x8 v0 = hv[(size_t)i0 * 8 + t];
        f16x8 v1 = hv[(size_t)i1 * 8 + t];
        f16x8 v2 = hv[(size_t)i2 * 8 + t];
        f16x8 v3 = hv[(size_t)i3 * 8 + t];
        #pragma unroll
        for (int j = 0; j < 8; ++j) {
            acc[j] += (float)v0[j];
            acc[j] = fmaf(m1, (float)v1[j], acc[j]);
            acc[j] = fmaf(m2, (float)v2[j], acc[j]);
            acc[j] = fmaf(m3, (float)v3[j], acc[j]);
        }
    }
    f16x8 o;
    #pragma unroll
    for (int j = 0; j < 8; ++j) o[j] = (f16)(acc[j] * fac);
    ((f16x8*)Xe)[(size_t)e * 8 + t] = o;
}

// Fused: Xv = (sum over incident edges of Xe[e]) * degV  ->  L2 rownorm ->
// GCNII mix -> 64x64 GEMM -> relu -> fp16. 8-lane-subgroup-per-vertex,
// 8-deep masked batch; indices via two int4 loads per batch.
__global__ __launch_bounds__(256) void k_vertex_update(const int* __restrict__ cntV,
                                                       const int* __restrict__ scrV,
                                                       const f16* __restrict__ Xe,
                                                       const float* __restrict__ degV,
                                                       const f16* __restrict__ h0,
                                                       const float* __restrict__ Wi,
                                                       float beta,
                                                       f16* __restrict__ h) {
    __shared__ float sW[NHID * NHID];    // 16 KB, row-major [k][f]
    for (int i = threadIdx.x; i < NHID * NHID; i += blockDim.x) sW[i] = Wi[i];
    __syncthreads();
    const int lane = threadIdx.x & 63;
    const int sg = lane >> 3, t = lane & 7;
    const int n = (blockIdx.x * 4 + (threadIdx.x >> 6)) * 8 + sg; // 32 verts/block
    if (n >= N_V) return;
    const f16x8* __restrict__ xe = (const f16x8*)Xe;
    const int cnt = min(cntV[n], MAXDV);
    const int base = n * MAXDV;
    const float dv = degV[n];
    const f16x8 h0v = ((const f16x8*)h0)[(size_t)n * 8 + t];
    float acc[8] = {0.f, 0.f, 0.f, 0.f, 0.f, 0.f, 0.f, 0.f};
    for (int w = 0; w < cnt; w += 8) {
        int4 qa = *(const int4*)&scrV[base + w];        // w multiple of 8 -> aligned
        int4 qb = *(const int4*)&scrV[base + w + 4];    // always in-row (w+7 <= 63)
        int   idx[8];
        float msk[8];
        idx[0] = qa.x;                       msk[0] = 1.f;   // w<cnt guaranteed
        idx[1] = (w + 1 < cnt) ? qa.y : qa.x; msk[1] = (w + 1 < cnt) ? 1.f : 0.f;
        idx[2] = (w + 2 < cnt) ? qa.z : qa.x; msk[2] = (w + 2 < cnt) ? 1.f : 0.f;
        idx[3] = (w + 3 < cnt) ? qa.w : qa.x; msk[3] = (w + 3 < cnt) ? 1.f : 0.f;
        idx[4] = (w + 4 < cnt) ? qb.x : qa.x; msk[4] = (w + 4 < cnt) ? 1.f : 0.f;
        idx[5] = (w + 5 < cnt) ? qb.y : qa.x; msk[5] = (w + 5 < cnt) ? 1.f : 0.f;
        idx[6] = (w + 6 < cnt) ? qb.z : qa.x; msk[6] = (w + 6 < cnt) ? 1.f : 0.f;
        idx[7] = (w + 7 < cnt) ? qb.w : qa.x; msk[7] = (w + 7 < cnt) ? 1.f : 0.f;
        f16x8 v[8];
        #pragma unroll
        for (int r = 0; r < 8; ++r) v[r] = xe[(size_t)idx[r] * 8 + t];
        #pragma unroll
        for (int j = 0; j < 8; ++j) {
            #pragma unroll
            for (int r = 0; r < 8; ++r)
                acc[j] = fmaf(msk[r], (float)v[r][j], acc[j]);
        }
    }
    // scale by degV FIRST, then norm of the scaled row (matches reference)
    float xv[8], ss = 0.f;
    #pragma unroll
    for (int j = 0; j < 8; ++j) { xv[j] = acc[j] * dv; ss = fmaf(xv[j], xv[j], ss); }
    #pragma unroll
    for (int off = 1; off <= 4; off <<= 1)   // reduce within the 8-lane subgroup
        ss += __shfl_xor(ss, off, 64);
    float rn  = sqrtf(ss);
    float inv = (rn > 0.0f) ? 1.0f / rn : 0.0f;
    float xi[8];
    #pragma unroll
    for (int j = 0; j < 8; ++j)
        xi[j] = (1.0f - ALPHA) * (xv[j] * inv) + ALPHA * (float)h0v[j];
    // y_f = sum_k xi_k * W[k][f], f = 8t+j; xi_k owned by lane 8*sg+(k>>3),
    // component k&7. Uniform k-loop; LDS float4 reads are 2-way alias (free).
    float y[8] = {0.f, 0.f, 0.f, 0.f, 0.f, 0.f, 0.f, 0.f};
    #pragma unroll
    for (int k = 0; k < NHID; ++k) {
        float xk = __shfl(xi[k & 7], 8 * sg + (k >> 3), 64);
        const float4 wa = *(const float4*)&sW[k * NHID + 8 * t];
        const float4 wb = *(const float4*)&sW[k * NHID + 8 * t + 4];
        y[0] = fmaf(xk, wa.x, y[0]);
        y[1] = fmaf(xk, wa.y, y[1]);
        y[2] = fmaf(xk, wa.z, y[2]);
        y[3] = fmaf(xk, wa.w, y[3]);
        y[4] = fmaf(xk, wb.x, y[4]);
        y[5] = fmaf(xk, wb.y, y[5]);
        y[6] = fmaf(xk, wb.z, y[6]);
        y[7] = fmaf(xk, wb.w, y[7]);
    }
    f16x8 o;
    #pragma unroll
    for (int j = 0; j < 8; ++j) {
        float v = fmaf(beta, y[j] - xi[j], xi[j]);   // (1-b)*xi + b*y
        o[j] = (f16)fmaxf(v, 0.0f);
    }
    ((f16x8*)h)[(size_t)n * 8 + t] = o;
}

// out = h @ Wout + bout.
// REWRITE (round 14): 8-lane subgroup per ROW PAIR (k_lin microstructure).
// Lane t holds h[r][8t..8t+7] from one f16x8 load; k-loop fully unrolled:
// 1 shuffle/row broadcasts h_k; lane t accumulates classes c = t+8i (i<5).
// Per-instruction W reads are 8 consecutive floats (conflict-free; 8-way
// cross-subgroup broadcast). Replaces the 64-deep serial shfl chain with
// 10 independent FMA chains and kills the 6.4M bank-conflict cycles.
__global__ __launch_bounds__(256) void k_out(const f16* __restrict__ h,
                                             const float* __restrict__ Wout,
                                             const float* __restrict__ bout,
                                             float* __restrict__ out) {
    __shared__ float sW[NHID * NCLASS];  // 10 KB, row-major [k][c]
    __shared__ float sb[NCLASS];
    for (int i = threadIdx.x; i < NHID * NCLASS; i += blockDim.x) sW[i] = Wout[i];
    if (threadIdx.x < NCLASS) sb[threadIdx.x] = bout[threadIdx.x];
    __syncthreads();
    const int lane   = threadIdx.x & 63;
    const int t      = lane & 7;
    const int sgbase = lane & 56;
    const int pair   = blockIdx.x * 32 + (threadIdx.x >> 3);  // 32 subgroups/block
    if (pair >= N_V / 2) return;                              // N_V even
    const int r0 = 2 * pair, r1 = r0 + 1;
    const f16x8 hv0 = ((const f16x8*)h)[(size_t)r0 * 8 + t];
    const f16x8 hv1 = ((const f16x8*)h)[(size_t)r1 * 8 + t];
    float h0r[8], h1r[8];
    #pragma unroll
    for (int j = 0; j < 8; ++j) { h0r[j] = (float)hv0[j]; h1r[j] = (float)hv1[j]; }
    // lane t owns classes c = t + 8*i  (t<8, i<5 -> covers all 40)
    float y0[5], y1[5];
    #pragma unroll
    for (int i = 0; i < 5; ++i) { y0[i] = sb[t + 8 * i]; y1[i] = y0[i]; }
    #pragma unroll
    for (int k = 0; k < NHID; ++k) {
        float hk0 = __shfl(h0r[k & 7], sgbase | (k >> 3), 64);
        float hk1 = __shfl(h1r[k & 7], sgbase | (k >> 3), 64);
        const float* wr = &sW[k * NCLASS];
        #pragma unroll
        for (int i = 0; i < 5; ++i) {
            float w = wr[t + 8 * i];
            y0[i] = fmaf(hk0, w, y0[i]);
            y1[i] = fmaf(hk1, w, y1[i]);
        }
    }
    #pragma unroll
    for (int i = 0; i < 5; ++i) {
        out[(size_t)r0 * NCLASS + t + 8 * i] = y0[i];
        out[(size_t)r1 * NCLASS + t + 8 * i] = y1[i];
    }
}

// ---------------------------------------------------------------------------
extern "C" void kernel_launch(void* const* d_in, const int* in_sizes, int n_in,
                              void* d_out, int out_size, void* d_ws, size_t ws_size,
                              hipStream_t stream) {
    const float* x      = (const float*)d_in[0];
    const int*   vertex = (const int*)  d_in[1];
    const int*   edges  = (const int*)  d_in[2];
    const float* degE   = (const float*)d_in[3];
    const float* degV   = (const float*)d_in[4];
    const float* W0     = (const float*)d_in[5];
    const float* b0     = (const float*)d_in[6];
    const float* Ws     = (const float*)d_in[7];
    const float* Wout   = (const float*)d_in[8];
    const float* bout   = (const float*)d_in[9];
    float* out = (float*)d_out;

    // workspace carve-up (~117 MB)
    char* p = (char*)d_ws;
    auto carve = [&](size_t bytes) { char* r = p; p += (bytes + 255) & ~(size_t)255; return r; };
    f16*   h0      = (f16*)  carve((size_t)N_V * NHID * sizeof(f16));    // 12.8 MB
    f16*   hA      = (f16*)  carve((size_t)N_V * NHID * sizeof(f16));    // 12.8 MB
    f16*   Xe      = (f16*)  carve((size_t)N_E * NHID * sizeof(f16));    // 25.6 MB
    float* factorE = (float*)carve((size_t)N_E * sizeof(float));         //  0.8 MB
    int*   cntE    = (int*)  carve((size_t)N_E * sizeof(int));           //  0.8 MB
    int*   cntV    = (int*)  carve((size_t)N_V * sizeof(int));           //  0.4 MB (contiguous after cntE)
    int*   scrE    = (int*)  carve((size_t)N_E * MAXDE * sizeof(int));   // 38.4 MB
    int*   scrV    = (int*)  carve((size_t)N_V * MAXDV * sizeof(int));   // 25.6 MB

    // ---- one-pass adjacency build (per call) ----
    // N_E*4 = 800000 B is 256-aligned, so cntV directly follows cntE:
    hipMemsetAsync(cntE, 0, (size_t)(N_E + N_V) * sizeof(int), stream);
    k_place_e<<<NWIN * 256, 256, 0, stream>>>(vertex, edges, cntE, scrE);
    k_place_v<<<NWIN * 256, 256, 0, stream>>>(vertex, edges, cntV, scrV);
    k_factor <<<(N_E + 255) / 256, 256, 0, stream>>>(cntE, degE, factorE);

    // ---- network ----
    k_lin<<<(N_V / 2 + 31) / 32, 256, 0, stream>>>(x, W0, b0, hA, h0);

    for (int i = 0; i < NLAYER; ++i) {
        float beta = (float)log(0.5 / (double)(i + 1) + 1.0);
        k_edge_gather  <<<(N_E + 31) / 32, 256, 0, stream>>>(cntE, scrE, factorE, hA, Xe);
        k_vertex_update<<<(N_V + 31) / 32, 256, 0, stream>>>(cntV, scrV, Xe, degV, h0,
                                                             Ws + (size_t)i * NHID * NHID,
                                                             beta, hA);
    }
    k_out<<<(N_V / 2 + 31) / 32, 256, 0, stream>>>(hA, Wout, bout, out);
}

// Round 15
// 927.111 us; speedup vs baseline: 1.3347x; 1.0062x over previous
//
#include <hip/hip_runtime.h>
#include <math.h>

#define N_V    100000
#define N_E    200000
#define NNZ_C  1600000
#define NFEAT  128
#define NHID   64
#define NCLASS 40
#define NLAYER 8
#define ALPHA  0.1f

#define NWIN   8                 // one window per XCD (blockIdx&7 round-robin)
#define WE     (N_E / NWIN)      // 25000 edges per window
#define WV     (N_V / NWIN)      // 12500 vertices per window

#define MAXDE  48                // scratch stride, edge lists  (Poisson(8):  P(>48) ~ 1e-24)
#define MAXDV  64                // scratch stride, vertex lists (Poisson(16): P(>64) ~ 1e-19)

typedef _Float16 f16;
typedef _Float16 f16x8 __attribute__((ext_vector_type(8)));   // 16 B per lane

// ---------------------------------------------------------------------------
// FUSED one-pass count+place, BOTH sides (round 15): k_place_e and k_place_v
// each streamed the same incidence arrays; fused kernel reads (v,e) once and
// does both window-conditional placements. p = atomicAdd(cnt[..]) is
// simultaneously histogram and slot. Window w handled only by blocks with
// blockIdx&7==w (round-robin => XCD-affine); each window's scratch slice
// (4.8 MB e-side, 3.2 MB v-side) stays L2-resident so 4 B stores merge.
__global__ __launch_bounds__(256) void k_place(const int* __restrict__ vertex,
                                               const int* __restrict__ edges,
                                               int* __restrict__ cntE,
                                               int* __restrict__ cntV,
                                               int* __restrict__ scrE,
                                               int* __restrict__ scrV) {
    const int win  = blockIdx.x & (NWIN - 1);
    const int blk  = blockIdx.x >> 3;
    const int nblk = gridDim.x >> 3;
    const int eLo = win * WE, eHi = eLo + WE;
    const int vLo = win * WV, vHi = vLo + WV;
    for (int z = blk * blockDim.x + threadIdx.x; z < NNZ_C; z += nblk * blockDim.x) {
        int v = __builtin_nontemporal_load(&vertex[z]);
        int e = __builtin_nontemporal_load(&edges[z]);
        if (e >= eLo && e < eHi) {
            int p = atomicAdd(&cntE[e], 1);
            if (p < MAXDE) scrE[e * MAXDE + p] = v;   // never triggers; safety
        }
        if (v >= vLo && v < vHi) {
            int p = atomicAdd(&cntV[v], 1);
            if (p < MAXDV) scrV[v * MAXDV + p] = e;
        }
    }
}

// factorE = degE / count (scatter-mean denom folded with degE)
__global__ __launch_bounds__(256) void k_factor(const int* __restrict__ cntE,
                                                const float* __restrict__ degE,
                                                float* __restrict__ factorE) {
    int e = blockIdx.x * blockDim.x + threadIdx.x;
    if (e < N_E) {
        int c = cntE[e];
        factorE[e] = (c > 0) ? degE[e] / (float)c : 0.0f;
    }
}

// h = relu(x @ W0 + b0) -> fp16; also copy to h0. (verified round 13)
// 8-lane subgroup per ROW PAIR; W row read shared 8-way; 16 indep FMA chains.
__global__ __launch_bounds__(256) void k_lin(const float* __restrict__ x,
                                             const float* __restrict__ W0,
                                             const float* __restrict__ b0,
                                             f16* __restrict__ h,
                                             f16* __restrict__ h0) {
    __shared__ float sW[NFEAT * NHID];   // 32 KB, row-major [k][f]
    __shared__ float sb[NHID];
    for (int i = threadIdx.x; i < NFEAT * NHID; i += blockDim.x) sW[i] = W0[i];
    if (threadIdx.x < NHID) sb[threadIdx.x] = b0[threadIdx.x];
    __syncthreads();
    const int lane = threadIdx.x & 63;
    const int t    = lane & 7;
    const int pair = blockIdx.x * 32 + (threadIdx.x >> 3);   // 32 subgroups/block
    if (pair >= N_V / 2) return;                              // N_V even
    const int r0 = 2 * pair, r1 = r0 + 1;
    const float4* __restrict__ x4 = (const float4*)x;         // 32 float4 per row
    float xr0[16], xr1[16];
    #pragma unroll
    for (int i = 0; i < 4; ++i) {
        float4 q0 = x4[(size_t)r0 * 32 + t * 4 + i];
        float4 q1 = x4[(size_t)r1 * 32 + t * 4 + i];
        xr0[4 * i + 0] = q0.x; xr0[4 * i + 1] = q0.y;
        xr0[4 * i + 2] = q0.z; xr0[4 * i + 3] = q0.w;
        xr1[4 * i + 0] = q1.x; xr1[4 * i + 1] = q1.y;
        xr1[4 * i + 2] = q1.z; xr1[4 * i + 3] = q1.w;
    }
    float a0[8], a1[8];
    #pragma unroll
    for (int j = 0; j < 8; ++j) { a0[j] = sb[8 * t + j]; a1[j] = a0[j]; }
    const int sgbase = lane & 56;        // subgroup base lane within wave
    #pragma unroll
    for (int k = 0; k < NFEAT; ++k) {
        float xk0 = __shfl(xr0[k & 15], sgbase | (k >> 4), 64);
        float xk1 = __shfl(xr1[k & 15], sgbase | (k >> 4), 64);
        const float4 wa = *(const float4*)&sW[k * NHID + 8 * t];
        const float4 wb = *(const float4*)&sW[k * NHID + 8 * t + 4];
        a0[0] = fmaf(xk0, wa.x, a0[0]);  a1[0] = fmaf(xk1, wa.x, a1[0]);
        a0[1] = fmaf(xk0, wa.y, a0[1]);  a1[1] = fmaf(xk1, wa.y, a1[1]);
        a0[2] = fmaf(xk0, wa.z, a0[2]);  a1[2] = fmaf(xk1, wa.z, a1[2]);
        a0[3] = fmaf(xk0, wa.w, a0[3]);  a1[3] = fmaf(xk1, wa.w, a1[3]);
        a0[4] = fmaf(xk0, wb.x, a0[4]);  a1[4] = fmaf(xk1, wb.x, a1[4]);
        a0[5] = fmaf(xk0, wb.y, a0[5]);  a1[5] = fmaf(xk1, wb.y, a1[5]);
        a0[6] = fmaf(xk0, wb.z, a0[6]);  a1[6] = fmaf(xk1, wb.z, a1[6]);
        a0[7] = fmaf(xk0, wb.w, a0[7]);  a1[7] = fmaf(xk1, wb.w, a1[7]);
    }
    f16x8 o0, o1;
    #pragma unroll
    for (int j = 0; j < 8; ++j) {
        o0[j] = (f16)fmaxf(a0[j], 0.0f);
        o1[j] = (f16)fmaxf(a1[j], 0.0f);
    }
    ((f16x8*)h )[(size_t)r0 * 8 + t] = o0;
    ((f16x8*)h )[(size_t)r1 * 8 + t] = o1;
    ((f16x8*)h0)[(size_t)r0 * 8 + t] = o0;
    ((f16x8*)h0)[(size_t)r1 * 8 + t] = o1;
}

// Xe[e] = (sum over incident vertices of h[v]) * factorE[e]
// 8-lane-subgroup-per-edge, 4-deep masked batch; indices come from the
// strided scratch row as ONE int4 load (16 B-aligned, always in-row).
__global__ __launch_bounds__(256) void k_edge_gather(const int* __restrict__ cntE,
                                                     const int* __restrict__ scrE,
                                                     const float* __restrict__ factorE,
                                                     const f16* __restrict__ h,
                                                     f16* __restrict__ Xe) {
    const int lane = threadIdx.x & 63;
    const int sg = lane >> 3, t = lane & 7;
    const int e = (blockIdx.x * 4 + (threadIdx.x >> 6)) * 8 + sg;  // 32 edges/block
    if (e >= N_E) return;
    const f16x8* __restrict__ hv = (const f16x8*)h;
    const int cnt = min(cntE[e], MAXDE);
    const int base = e * MAXDE;
    const float fac = factorE[e];
    float acc[8] = {0.f, 0.f, 0.f, 0.f, 0.f, 0.f, 0.f, 0.f};
    for (int w = 0; w < cnt; w += 4) {
        int4 q = *(const int4*)&scrE[base + w];     // slots w..w+3 (w<cnt => q.x valid)
        int i0 = q.x;
        int i1 = (w + 1 < cnt) ? q.y : q.x;         // clamp garbage slots to a valid idx
        int i2 = (w + 2 < cnt) ? q.z : q.x;
        int i3 = (w + 3 < cnt) ? q.w : q.x;
        float m1 = (w + 1 < cnt) ? 1.f : 0.f;
        float m2 = (w + 2 < cnt) ? 1.f : 0.f;
        float m3 = (w + 3 < cnt) ? 1.f : 0.f;
        f16x8 v0 = hv[(size_t)i0 * 8 + t];
        f16x8 v1 = hv[(size_t)i1 * 8 + t];
        f16x8 v2 = hv[(size_t)i2 * 8 + t];
        f16x8 v3 = hv[(size_t)i3 * 8 + t];
        #pragma unroll
        for (int j = 0; j < 8; ++j) {
            acc[j] += (float)v0[j];
            acc[j] = fmaf(m1, (float)v1[j], acc[j]);
            acc[j] = fmaf(m2, (float)v2[j], acc[j]);
            acc[j] = fmaf(m3, (float)v3[j], acc[j]);
        }
    }
    f16x8 o;
    #pragma unroll
    for (int j = 0; j < 8; ++j) o[j] = (f16)(acc[j] * fac);
    ((f16x8*)Xe)[(size_t)e * 8 + t] = o;
}

// Fused: Xv = (sum over incident edges of Xe[e]) * degV  ->  L2 rownorm ->
// GCNII mix -> 64x64 GEMM -> relu -> fp16. 8-lane-subgroup-per-vertex,
// 8-deep masked batch; indices via two int4 loads per batch.
__global__ __launch_bounds__(256) void k_vertex_update(const int* __restrict__ cntV,
                                                       const int* __restrict__ scrV,
                                                       const f16* __restrict__ Xe,
                                                       const float* __restrict__ degV,
                                                       const f16* __restrict__ h0,
                                                       const float* __restrict__ Wi,
                                                       float beta,
                                                       f16* __restrict__ h) {
    __shared__ float sW[NHID * NHID];    // 16 KB, row-major [k][f]
    for (int i = threadIdx.x; i < NHID * NHID; i += blockDim.x) sW[i] = Wi[i];
    __syncthreads();
    const int lane = threadIdx.x & 63;
    const int sg = lane >> 3, t = lane & 7;
    const int n = (blockIdx.x * 4 + (threadIdx.x >> 6)) * 8 + sg; // 32 verts/block
    if (n >= N_V) return;
    const f16x8* __restrict__ xe = (const f16x8*)Xe;
    const int cnt = min(cntV[n], MAXDV);
    const int base = n * MAXDV;
    const float dv = degV[n];
    const f16x8 h0v = ((const f16x8*)h0)[(size_t)n * 8 + t];
    float acc[8] = {0.f, 0.f, 0.f, 0.f, 0.f, 0.f, 0.f, 0.f};
    for (int w = 0; w < cnt; w += 8) {
        int4 qa = *(const int4*)&scrV[base + w];        // w multiple of 8 -> aligned
        int4 qb = *(const int4*)&scrV[base + w + 4];    // always in-row (w+7 <= 63)
        int   idx[8];
        float msk[8];
        idx[0] = qa.x;                       msk[0] = 1.f;   // w<cnt guaranteed
        idx[1] = (w + 1 < cnt) ? qa.y : qa.x; msk[1] = (w + 1 < cnt) ? 1.f : 0.f;
        idx[2] = (w + 2 < cnt) ? qa.z : qa.x; msk[2] = (w + 2 < cnt) ? 1.f : 0.f;
        idx[3] = (w + 3 < cnt) ? qa.w : qa.x; msk[3] = (w + 3 < cnt) ? 1.f : 0.f;
        idx[4] = (w + 4 < cnt) ? qb.x : qa.x; msk[4] = (w + 4 < cnt) ? 1.f : 0.f;
        idx[5] = (w + 5 < cnt) ? qb.y : qa.x; msk[5] = (w + 5 < cnt) ? 1.f : 0.f;
        idx[6] = (w + 6 < cnt) ? qb.z : qa.x; msk[6] = (w + 6 < cnt) ? 1.f : 0.f;
        idx[7] = (w + 7 < cnt) ? qb.w : qa.x; msk[7] = (w + 7 < cnt) ? 1.f : 0.f;
        f16x8 v[8];
        #pragma unroll
        for (int r = 0; r < 8; ++r) v[r] = xe[(size_t)idx[r] * 8 + t];
        #pragma unroll
        for (int j = 0; j < 8; ++j) {
            #pragma unroll
            for (int r = 0; r < 8; ++r)
                acc[j] = fmaf(msk[r], (float)v[r][j], acc[j]);
        }
    }
    // scale by degV FIRST, then norm of the scaled row (matches reference)
    float xv[8], ss = 0.f;
    #pragma unroll
    for (int j = 0; j < 8; ++j) { xv[j] = acc[j] * dv; ss = fmaf(xv[j], xv[j], ss); }
    #pragma unroll
    for (int off = 1; off <= 4; off <<= 1)   // reduce within the 8-lane subgroup
        ss += __shfl_xor(ss, off, 64);
    float rn  = sqrtf(ss);
    float inv = (rn > 0.0f) ? 1.0f / rn : 0.0f;
    float xi[8];
    #pragma unroll
    for (int j = 0; j < 8; ++j)
        xi[j] = (1.0f - ALPHA) * (xv[j] * inv) + ALPHA * (float)h0v[j];
    // y_f = sum_k xi_k * W[k][f], f = 8t+j; xi_k owned by lane 8*sg+(k>>3),
    // component k&7. Uniform k-loop; LDS float4 reads are 2-way alias (free).
    float y[8] = {0.f, 0.f, 0.f, 0.f, 0.f, 0.f, 0.f, 0.f};
    #pragma unroll
    for (int k = 0; k < NHID; ++k) {
        float xk = __shfl(xi[k & 7], 8 * sg + (k >> 3), 64);
        const float4 wa = *(const float4*)&sW[k * NHID + 8 * t];
        const float4 wb = *(const float4*)&sW[k * NHID + 8 * t + 4];
        y[0] = fmaf(xk, wa.x, y[0]);
        y[1] = fmaf(xk, wa.y, y[1]);
        y[2] = fmaf(xk, wa.z, y[2]);
        y[3] = fmaf(xk, wa.w, y[3]);
        y[4] = fmaf(xk, wb.x, y[4]);
        y[5] = fmaf(xk, wb.y, y[5]);
        y[6] = fmaf(xk, wb.z, y[6]);
        y[7] = fmaf(xk, wb.w, y[7]);
    }
    f16x8 o;
    #pragma unroll
    for (int j = 0; j < 8; ++j) {
        float v = fmaf(beta, y[j] - xi[j], xi[j]);   // (1-b)*xi + b*y
        o[j] = (f16)fmaxf(v, 0.0f);
    }
    ((f16x8*)h)[(size_t)n * 8 + t] = o;
}

// out = h @ Wout + bout. (verified round 14)
// 8-lane subgroup per ROW PAIR; lane t owns classes c = t+8i (i<5).
__global__ __launch_bounds__(256) void k_out(const f16* __restrict__ h,
                                             const float* __restrict__ Wout,
                                             const float* __restrict__ bout,
                                             float* __restrict__ out) {
    __shared__ float sW[NHID * NCLASS];  // 10 KB, row-major [k][c]
    __shared__ float sb[NCLASS];
    for (int i = threadIdx.x; i < NHID * NCLASS; i += blockDim.x) sW[i] = Wout[i];
    if (threadIdx.x < NCLASS) sb[threadIdx.x] = bout[threadIdx.x];
    __syncthreads();
    const int lane   = threadIdx.x & 63;
    const int t      = lane & 7;
    const int sgbase = lane & 56;
    const int pair   = blockIdx.x * 32 + (threadIdx.x >> 3);  // 32 subgroups/block
    if (pair >= N_V / 2) return;                              // N_V even
    const int r0 = 2 * pair, r1 = r0 + 1;
    const f16x8 hv0 = ((const f16x8*)h)[(size_t)r0 * 8 + t];
    const f16x8 hv1 = ((const f16x8*)h)[(size_t)r1 * 8 + t];
    float h0r[8], h1r[8];
    #pragma unroll
    for (int j = 0; j < 8; ++j) { h0r[j] = (float)hv0[j]; h1r[j] = (float)hv1[j]; }
    float y0[5], y1[5];
    #pragma unroll
    for (int i = 0; i < 5; ++i) { y0[i] = sb[t + 8 * i]; y1[i] = y0[i]; }
    #pragma unroll
    for (int k = 0; k < NHID; ++k) {
        float hk0 = __shfl(h0r[k & 7], sgbase | (k >> 3), 64);
        float hk1 = __shfl(h1r[k & 7], sgbase | (k >> 3), 64);
        const float* wr = &sW[k * NCLASS];
        #pragma unroll
        for (int i = 0; i < 5; ++i) {
            float w = wr[t + 8 * i];
            y0[i] = fmaf(hk0, w, y0[i]);
            y1[i] = fmaf(hk1, w, y1[i]);
        }
    }
    #pragma unroll
    for (int i = 0; i < 5; ++i) {
        out[(size_t)r0 * NCLASS + t + 8 * i] = y0[i];
        out[(size_t)r1 * NCLASS + t + 8 * i] = y1[i];
    }
}

// ---------------------------------------------------------------------------
extern "C" void kernel_launch(void* const* d_in, const int* in_sizes, int n_in,
                              void* d_out, int out_size, void* d_ws, size_t ws_size,
                              hipStream_t stream) {
    const float* x      = (const float*)d_in[0];
    const int*   vertex = (const int*)  d_in[1];
    const int*   edges  = (const int*)  d_in[2];
    const float* degE   = (const float*)d_in[3];
    const float* degV   = (const float*)d_in[4];
    const float* W0     = (const float*)d_in[5];
    const float* b0     = (const float*)d_in[6];
    const float* Ws     = (const float*)d_in[7];
    const float* Wout   = (const float*)d_in[8];
    const float* bout   = (const float*)d_in[9];
    float* out = (float*)d_out;

    // workspace carve-up (~117 MB)
    char* p = (char*)d_ws;
    auto carve = [&](size_t bytes) { char* r = p; p += (bytes + 255) & ~(size_t)255; return r; };
    f16*   h0      = (f16*)  carve((size_t)N_V * NHID * sizeof(f16));    // 12.8 MB
    f16*   hA      = (f16*)  carve((size_t)N_V * NHID * sizeof(f16));    // 12.8 MB
    f16*   Xe      = (f16*)  carve((size_t)N_E * NHID * sizeof(f16));    // 25.6 MB
    float* factorE = (float*)carve((size_t)N_E * sizeof(float));         //  0.8 MB
    int*   cntE    = (int*)  carve((size_t)N_E * sizeof(int));           //  0.8 MB
    int*   cntV    = (int*)  carve((size_t)N_V * sizeof(int));           //  0.4 MB (contiguous after cntE)
    int*   scrE    = (int*)  carve((size_t)N_E * MAXDE * sizeof(int));   // 38.4 MB
    int*   scrV    = (int*)  carve((size_t)N_V * MAXDV * sizeof(int));   // 25.6 MB

    // ---- one-pass adjacency build (per call) ----
    // N_E*4 = 800000 B is 256-aligned, so cntV directly follows cntE:
    hipMemsetAsync(cntE, 0, (size_t)(N_E + N_V) * sizeof(int), stream);
    k_place <<<NWIN * 256, 256, 0, stream>>>(vertex, edges, cntE, cntV, scrE, scrV);
    k_factor<<<(N_E + 255) / 256, 256, 0, stream>>>(cntE, degE, factorE);

    // ---- network ----
    k_lin<<<(N_V / 2 + 31) / 32, 256, 0, stream>>>(x, W0, b0, hA, h0);

    for (int i = 0; i < NLAYER; ++i) {
        float beta = (float)log(0.5 / (double)(i + 1) + 1.0);
        k_edge_gather  <<<(N_E + 31) / 32, 256, 0, stream>>>(cntE, scrE, factorE, hA, Xe);
        k_vertex_update<<<(N_V + 31) / 32, 256, 0, stream>>>(cntV, scrV, Xe, degV, h0,
                                                             Ws + (size_t)i * NHID * NHID,
                                                             beta, hA);
    }
    k_out<<<(N_V / 2 + 31) / 32, 256, 0, stream>>>(hA, Wout, bout, out);
}